// Round 2
// baseline (8556.040 us; speedup 1.0000x reference)
//
#include <hip/hip_runtime.h>
#include <hip/hip_bf16.h>
#include <math.h>

#define QMAX 127.0f

// ---- absmax slots (uint-as-float bits) ----
// 0: ln1 y   2: xa(bf16)   3: h(gelu,bf16)   4: ln2 y
// 6: qkv_w   7: proj_w     8: fc1_w          9: fc2_w

__device__ inline float bf2f(unsigned short u) {
    return __uint_as_float(((unsigned int)u) << 16);
}
__device__ inline unsigned short f2bf(float f) {
    __hip_bfloat16 h = __float2bfloat16(f);   // round-to-nearest-even
    return *reinterpret_cast<unsigned short*>(&h);
}

__global__ void init_slots(unsigned int* am) {
    if (threadIdx.x < 16) am[threadIdx.x] = 0u;
}

// ---------------- absmax over fp32 array ----------------
__global__ __launch_bounds__(256) void absmax_f32(
    const float* __restrict__ p, size_t n, unsigned int* __restrict__ slot)
{
    float lmax = 0.f;
    for (size_t i = (size_t)blockIdx.x*256 + threadIdx.x; i < n; i += (size_t)gridDim.x*256)
        lmax = fmaxf(lmax, fabsf(p[i]));
    __shared__ float rs[256];
    int t = threadIdx.x;
    rs[t] = lmax; __syncthreads();
    for (int o = 128; o; o >>= 1) {
        if (t < o) rs[t] = fmaxf(rs[t], rs[t+o]);
        __syncthreads();
    }
    if (t == 0) atomicMax(slot, __float_as_uint(rs[0]));
}

// ---------------- weight quantize: fp32 -> int8 ----------------
__global__ __launch_bounds__(256) void quant_w(
    const float* __restrict__ w, char* __restrict__ q, size_t n,
    const unsigned int* __restrict__ slot)
{
    float s = __uint_as_float(*slot) / QMAX + 1e-8f;
    for (size_t i = (size_t)blockIdx.x*256 + threadIdx.x; i < n; i += (size_t)gridDim.x*256) {
        float k = fminf(fmaxf(rintf(w[i] / s), -QMAX), QMAX);
        q[i] = (char)(int)k;
    }
}

// ---------------- LayerNorm pass 1: absmax(y) only ----------------
__global__ __launch_bounds__(256) void ln_absmax(
    const float* __restrict__ x, const float* __restrict__ g, const float* __restrict__ bia,
    unsigned int* __restrict__ slot)
{
    const int C = 768;
    int row = blockIdx.x, t = threadIdx.x;
    const float* xr = x + (size_t)row * C;
    float v0 = xr[t], v1 = xr[t+256], v2 = xr[t+512];
    __shared__ float rs[256], rss[256];
    rs[t] = v0+v1+v2; rss[t] = v0*v0+v1*v1+v2*v2; __syncthreads();
    for (int o = 128; o; o >>= 1) {
        if (t < o) { rs[t] += rs[t+o]; rss[t] += rss[t+o]; }
        __syncthreads();
    }
    float mean = rs[0] * (1.0f/768.0f);
    float var  = rss[0] * (1.0f/768.0f) - mean*mean;
    float inv  = rsqrtf(var + 1e-6f);
    float y0 = (v0-mean)*inv*g[t]     + bia[t];
    float y1 = (v1-mean)*inv*g[t+256] + bia[t+256];
    float y2 = (v2-mean)*inv*g[t+512] + bia[t+512];
    float lmax = fmaxf(fabsf(y0), fmaxf(fabsf(y1), fabsf(y2)));
    __syncthreads();
    rs[t] = lmax; __syncthreads();
    for (int o = 128; o; o >>= 1) {
        if (t < o) rs[t] = fmaxf(rs[t], rs[t+o]);
        __syncthreads();
    }
    if (t == 0) atomicMax(slot, __float_as_uint(rs[0]));
}

// ---------------- LayerNorm pass 2: recompute y, emit int8 k = clip(round(y/s1)) ----------------
__global__ __launch_bounds__(256) void ln_quant(
    const float* __restrict__ x, const float* __restrict__ g, const float* __restrict__ bia,
    char* __restrict__ yq, const unsigned int* __restrict__ slot)
{
    const int C = 768;
    int row = blockIdx.x, t = threadIdx.x;
    const float* xr = x + (size_t)row * C;
    float v0 = xr[t], v1 = xr[t+256], v2 = xr[t+512];
    __shared__ float rs[256], rss[256];
    rs[t] = v0+v1+v2; rss[t] = v0*v0+v1*v1+v2*v2; __syncthreads();
    for (int o = 128; o; o >>= 1) {
        if (t < o) { rs[t] += rs[t+o]; rss[t] += rss[t+o]; }
        __syncthreads();
    }
    float mean = rs[0] * (1.0f/768.0f);
    float var  = rss[0] * (1.0f/768.0f) - mean*mean;
    float inv  = rsqrtf(var + 1e-6f);
    float s1 = __uint_as_float(*slot) / QMAX + 1e-8f;
    float y0 = (v0-mean)*inv*g[t]     + bia[t];
    float y1 = (v1-mean)*inv*g[t+256] + bia[t+256];
    float y2 = (v2-mean)*inv*g[t+512] + bia[t+512];
    char* yr = yq + (size_t)row * C;
    yr[t]     = (char)(int)fminf(fmaxf(rintf(y0/s1), -QMAX), QMAX);
    yr[t+256] = (char)(int)fminf(fmaxf(rintf(y1/s1), -QMAX), QMAX);
    yr[t+512] = (char)(int)fminf(fmaxf(rintf(y2/s1), -QMAX), QMAX);
}

// ---------------- GEMM: out[m,n] = sA*sW * sum_k kA[m,k]*kW[n,k] + bias[n] ----------------
// AMODE 0: A is int8 (k values). AMODE 1: A is bf16, quantized on the fly with sA.
// LDS holds integer-valued floats; fp32 accumulation of integer products is exact (K=768).
#define BM 64
#define BN 64
#define BK 16
template<int AMODE>
__global__ __launch_bounds__(256) void gemm_q(
    const void* __restrict__ Aptr, const char* __restrict__ Wq,
    const float* __restrict__ bias, const float* __restrict__ residual,
    void* __restrict__ outp, int M, int N, int K,
    const unsigned int* __restrict__ slotA, float epsA,
    const unsigned int* __restrict__ slotW,
    int apply_gelu, int out_bf16, unsigned int* __restrict__ am_slot)
{
    __shared__ __align__(16) float As[BK][BM];
    __shared__ __align__(16) float Ws[BK][BN];
    __shared__ float sred[256];
    float sA = __uint_as_float(*slotA) / QMAX + epsA;
    float sW = __uint_as_float(*slotW) / QMAX + 1e-8f;
    int t  = threadIdx.x;
    int tx = t & 15;
    int ty = t >> 4;
    int n0 = blockIdx.x * BN;
    int m0 = blockIdx.y * BM;
    int li = t >> 2;              // row in tile [0,64)
    int lj = (t & 3) * 4;         // k-offset {0,4,8,12}
    float acc[4][4] = {};
    for (int k0 = 0; k0 < K; k0 += BK) {
        {
            int gm = m0 + li;
            float a0=0.f, a1=0.f, a2=0.f, a3=0.f;
            if (gm < M) {
                if (AMODE == 0) {
                    char4 v = *reinterpret_cast<const char4*>(
                        (const char*)Aptr + (size_t)gm*K + k0 + lj);
                    a0 = (float)v.x; a1 = (float)v.y; a2 = (float)v.z; a3 = (float)v.w;
                } else {
                    ushort4 u = *reinterpret_cast<const ushort4*>(
                        (const unsigned short*)Aptr + (size_t)gm*K + k0 + lj);
                    a0 = fminf(fmaxf(rintf(bf2f(u.x)/sA), -QMAX), QMAX);
                    a1 = fminf(fmaxf(rintf(bf2f(u.y)/sA), -QMAX), QMAX);
                    a2 = fminf(fmaxf(rintf(bf2f(u.z)/sA), -QMAX), QMAX);
                    a3 = fminf(fmaxf(rintf(bf2f(u.w)/sA), -QMAX), QMAX);
                }
            }
            As[lj+0][li] = a0; As[lj+1][li] = a1; As[lj+2][li] = a2; As[lj+3][li] = a3;
            int gn = n0 + li;     // N always a multiple of 64
            char4 w = *reinterpret_cast<const char4*>(Wq + (size_t)gn*K + k0 + lj);
            Ws[lj+0][li] = (float)w.x; Ws[lj+1][li] = (float)w.y;
            Ws[lj+2][li] = (float)w.z; Ws[lj+3][li] = (float)w.w;
        }
        __syncthreads();
        #pragma unroll
        for (int kk = 0; kk < BK; ++kk) {
            float4 av = *reinterpret_cast<const float4*>(&As[kk][ty*4]);
            float4 bv = *reinterpret_cast<const float4*>(&Ws[kk][tx*4]);
            float a[4] = {av.x, av.y, av.z, av.w};
            float b[4] = {bv.x, bv.y, bv.z, bv.w};
            #pragma unroll
            for (int i = 0; i < 4; ++i)
                #pragma unroll
                for (int j = 0; j < 4; ++j)
                    acc[i][j] += a[i] * b[j];
        }
        __syncthreads();
    }
    float scale = sA * sW;
    float lmax = 0.f;
    #pragma unroll
    for (int i = 0; i < 4; ++i) {
        int m = m0 + ty*4 + i;
        if (m >= M) continue;
        #pragma unroll
        for (int j = 0; j < 4; ++j) {
            int n = n0 + tx*4 + j;
            float v = scale * acc[i][j] + bias[n];
            if (residual) v += residual[(size_t)m*N + n];
            if (apply_gelu) v = 0.5f * v * (1.0f + erff(v * 0.70710678118654752f));
            if (out_bf16) {
                unsigned short ub = f2bf(v);
                ((unsigned short*)outp)[(size_t)m*N + n] = ub;
                lmax = fmaxf(lmax, fabsf(bf2f(ub)));
            } else {
                ((float*)outp)[(size_t)m*N + n] = v;
                lmax = fmaxf(lmax, fabsf(v));
            }
        }
    }
    if (am_slot) {
        sred[t] = lmax; __syncthreads();
        for (int o = 128; o; o >>= 1) {
            if (t < o) sred[t] = fmaxf(sred[t], sred[t+o]);
            __syncthreads();
        }
        if (t == 0) atomicMax(am_slot, __float_as_uint(sred[0]));
    }
}

// ---------------- attention: one wave per (b,h,query-row); bf16 qkv in, bf16 xa out ----------------
__global__ __launch_bounds__(64) void attn_kernel(
    const unsigned short* __restrict__ qkv, unsigned short* __restrict__ xa,
    unsigned int* __restrict__ am_slot)
{
    const int Nn = 577;
    int bid  = blockIdx.x;
    int nq   = bid % Nn;
    int tmp  = bid / Nn;
    int h    = tmp % 12;
    int b    = tmp / 12;
    int lane = threadIdx.x;

    __shared__ float qs[64];
    __shared__ float scores[577];

    const unsigned short* qrow = qkv + ((size_t)(b*Nn + nq))*2304 + h*64;
    qs[lane] = bf2f(qrow[lane]) * 0.125f;      // fold in d^-0.5
    __syncthreads();

    for (int m = lane; m < Nn; m += 64) {
        const ushort4* kp = reinterpret_cast<const ushort4*>(
            qkv + ((size_t)(b*Nn + m))*2304 + 768 + h*64);
        float acc = 0.f;
        #pragma unroll
        for (int dd = 0; dd < 16; ++dd) {
            ushort4 kv = kp[dd];
            acc += qs[dd*4+0]*bf2f(kv.x) + qs[dd*4+1]*bf2f(kv.y)
                 + qs[dd*4+2]*bf2f(kv.z) + qs[dd*4+3]*bf2f(kv.w);
        }
        scores[m] = acc;
    }
    __syncthreads();

    float mx = -INFINITY;
    for (int m = lane; m < Nn; m += 64) mx = fmaxf(mx, scores[m]);
    for (int off = 32; off; off >>= 1) mx = fmaxf(mx, __shfl_xor(mx, off));

    float sum = 0.f;
    for (int m = lane; m < Nn; m += 64) {
        float e = expf(scores[m] - mx);
        scores[m] = e;
        sum += e;
    }
    for (int off = 32; off; off >>= 1) sum += __shfl_xor(sum, off);
    __syncthreads();   // scores[] fully written before cross-lane reads

    float o = 0.f;
    for (int m = 0; m < Nn; ++m) {
        const unsigned short* vrow = qkv + ((size_t)(b*Nn + m))*2304 + 1536 + h*64;
        o += scores[m] * bf2f(vrow[lane]);
    }
    o /= sum;
    unsigned short ob = f2bf(o);
    xa[((size_t)(b*Nn + nq))*768 + h*64 + lane] = ob;

    float am = fabsf(bf2f(ob));
    for (int off = 32; off; off >>= 1) am = fmaxf(am, __shfl_xor(am, off));
    if (lane == 0) atomicMax(am_slot, __float_as_uint(am));
}

extern "C" void kernel_launch(void* const* d_in, const int* in_sizes, int n_in,
                              void* d_out, int out_size, void* d_ws, size_t ws_size,
                              hipStream_t stream)
{
    const float* x      = (const float*)d_in[0];
    const float* ln1_g  = (const float*)d_in[1];
    const float* ln1_b  = (const float*)d_in[2];
    const float* qkv_w  = (const float*)d_in[3];
    const float* qkv_b  = (const float*)d_in[4];
    const float* proj_w = (const float*)d_in[5];
    const float* proj_b = (const float*)d_in[6];
    const float* ln2_g  = (const float*)d_in[7];
    const float* ln2_b  = (const float*)d_in[8];
    const float* fc1_w  = (const float*)d_in[9];
    const float* fc1_b  = (const float*)d_in[10];
    const float* fc2_w  = (const float*)d_in[11];
    const float* fc2_b  = (const float*)d_in[12];
    float* out = (float*)d_out;

    const int B = 32, Nn = 577, C = 768, H3 = 3072;
    const int M = B * Nn;                   // 18464
    const size_t nA = (size_t)M * C;        // 14,180,352
    const size_t nQ = (size_t)M * 3 * C;    // 42,541,056
    const size_t nH = (size_t)M * H3;       // 56,721,408 = nQ + nA

    // ---- workspace layout (bytes) ----
    // [0,256)                  : absmax slots
    // [256, +2359296)          : WQ  int8 (just-in-time quantized weight, max 3072*768)
    // [.. , +nA)               : XNQ int8 (quantized LN output; reused ln1 -> ln2)
    // [.. , +2*nH)             : BIG bf16: phase A = QKV(2*nQ) | XA(2*nA); phase B = H(2*nH)
    const size_t NEEDED = 256 + 2359296 + nA + 2*nH;   // 129,982,720 B
    if (ws_size < NEEDED) return;   // diagnosable wrong-output instead of a crash

    char* wsb = (char*)d_ws;
    unsigned int* am = (unsigned int*)wsb;
    char* WQ  = wsb + 256;
    char* XNQ = WQ + 2359296;
    char* BIG = XNQ + nA;
    unsigned short* QKV = (unsigned short*)BIG;
    unsigned short* XA  = (unsigned short*)(BIG + 2*nQ);
    unsigned short* Hbf = (unsigned short*)BIG;

    dim3 blk(256);
    int mblocks = (M + 63) / 64;   // 289

    init_slots<<<dim3(1), dim3(16), 0, stream>>>(am);

    // ---- attention branch ----
    ln_absmax<<<dim3(M), blk, 0, stream>>>(x, ln1_g, ln1_b, am + 0);
    ln_quant <<<dim3(M), blk, 0, stream>>>(x, ln1_g, ln1_b, XNQ, am + 0);

    absmax_f32<<<dim3(1024), blk, 0, stream>>>(qkv_w, (size_t)3*C*C, am + 6);
    quant_w  <<<dim3(1024), blk, 0, stream>>>(qkv_w, WQ, (size_t)3*C*C, am + 6);
    gemm_q<0><<<dim3(3*C/64, mblocks), blk, 0, stream>>>(
        XNQ, WQ, qkv_b, nullptr, QKV, M, 3*C, C,
        am + 0, 2e-8f, am + 6, 0, 1, nullptr);

    attn_kernel<<<dim3(B*12*Nn), dim3(64), 0, stream>>>(QKV, XA, am + 2);

    absmax_f32<<<dim3(1024), blk, 0, stream>>>(proj_w, (size_t)C*C, am + 7);
    quant_w  <<<dim3(1024), blk, 0, stream>>>(proj_w, WQ, (size_t)C*C, am + 7);
    gemm_q<1><<<dim3(C/64, mblocks), blk, 0, stream>>>(
        XA, WQ, proj_b, x, out, M, C, C,
        am + 2, 1e-8f, am + 7, 0, 0, nullptr);          // out = x + proj

    // ---- mlp branch ----
    ln_absmax<<<dim3(M), blk, 0, stream>>>(out, ln2_g, ln2_b, am + 4);
    ln_quant <<<dim3(M), blk, 0, stream>>>(out, ln2_g, ln2_b, XNQ, am + 4);

    absmax_f32<<<dim3(1024), blk, 0, stream>>>(fc1_w, (size_t)H3*C, am + 8);
    quant_w  <<<dim3(1024), blk, 0, stream>>>(fc1_w, WQ, (size_t)H3*C, am + 8);
    gemm_q<0><<<dim3(H3/64, mblocks), blk, 0, stream>>>(
        XNQ, WQ, fc1_b, nullptr, Hbf, M, H3, C,
        am + 4, 2e-8f, am + 8, 1, 1, am + 3);           // gelu, bf16 out, absmax(h)

    absmax_f32<<<dim3(1024), blk, 0, stream>>>(fc2_w, (size_t)C*H3, am + 9);
    quant_w  <<<dim3(1024), blk, 0, stream>>>(fc2_w, WQ, (size_t)C*H3, am + 9);
    gemm_q<1><<<dim3(C/64, mblocks), blk, 0, stream>>>(
        Hbf, WQ, fc2_b, out, out, M, C, H3,
        am + 3, 1e-8f, am + 9, 0, 0, nullptr);          // out += fc2
}

// Round 3
// 5332.930 us; speedup vs baseline: 1.6044x; 1.6044x over previous
//
#include <hip/hip_runtime.h>
#include <hip/hip_bf16.h>
#include <math.h>

#define QMAX 127.0f

// ---- absmax slots (uint-as-float bits) ----
// 0: ln1 y   2: xa(bf16)   3: h(gelu,bf16)   4: ln2 y
// 6: qkv_w   7: proj_w     8: fc1_w          9: fc2_w

typedef unsigned short ushortx8 __attribute__((ext_vector_type(8)));

__device__ inline float bf2f(unsigned short u) {
    return __uint_as_float(((unsigned int)u) << 16);
}
__device__ inline unsigned short f2bf(float f) {
    __hip_bfloat16 h = __float2bfloat16(f);   // round-to-nearest-even
    return *reinterpret_cast<unsigned short*>(&h);
}

__global__ void init_slots(unsigned int* am) {
    if (threadIdx.x < 16) am[threadIdx.x] = 0u;
}

// ---------------- absmax over fp32 array ----------------
__global__ __launch_bounds__(256) void absmax_f32(
    const float* __restrict__ p, size_t n, unsigned int* __restrict__ slot)
{
    float lmax = 0.f;
    for (size_t i = (size_t)blockIdx.x*256 + threadIdx.x; i < n; i += (size_t)gridDim.x*256)
        lmax = fmaxf(lmax, fabsf(p[i]));
    __shared__ float rs[256];
    int t = threadIdx.x;
    rs[t] = lmax; __syncthreads();
    for (int o = 128; o; o >>= 1) {
        if (t < o) rs[t] = fmaxf(rs[t], rs[t+o]);
        __syncthreads();
    }
    if (t == 0) atomicMax(slot, __float_as_uint(rs[0]));
}

// ---------------- weight quantize: fp32 -> int8 ----------------
__global__ __launch_bounds__(256) void quant_w(
    const float* __restrict__ w, char* __restrict__ q, size_t n,
    const unsigned int* __restrict__ slot)
{
    float s = __uint_as_float(*slot) / QMAX + 1e-8f;
    for (size_t i = (size_t)blockIdx.x*256 + threadIdx.x; i < n; i += (size_t)gridDim.x*256) {
        float k = fminf(fmaxf(rintf(w[i] / s), -QMAX), QMAX);
        q[i] = (char)(int)k;
    }
}

// ---------------- LayerNorm pass 1: absmax(y) only ----------------
__global__ __launch_bounds__(256) void ln_absmax(
    const float* __restrict__ x, const float* __restrict__ g, const float* __restrict__ bia,
    unsigned int* __restrict__ slot)
{
    const int C = 768;
    int row = blockIdx.x, t = threadIdx.x;
    const float* xr = x + (size_t)row * C;
    float v0 = xr[t], v1 = xr[t+256], v2 = xr[t+512];
    __shared__ float rs[256], rss[256];
    rs[t] = v0+v1+v2; rss[t] = v0*v0+v1*v1+v2*v2; __syncthreads();
    for (int o = 128; o; o >>= 1) {
        if (t < o) { rs[t] += rs[t+o]; rss[t] += rss[t+o]; }
        __syncthreads();
    }
    float mean = rs[0] * (1.0f/768.0f);
    float var  = rss[0] * (1.0f/768.0f) - mean*mean;
    float inv  = rsqrtf(var + 1e-6f);
    float y0 = (v0-mean)*inv*g[t]     + bia[t];
    float y1 = (v1-mean)*inv*g[t+256] + bia[t+256];
    float y2 = (v2-mean)*inv*g[t+512] + bia[t+512];
    float lmax = fmaxf(fabsf(y0), fmaxf(fabsf(y1), fabsf(y2)));
    __syncthreads();
    rs[t] = lmax; __syncthreads();
    for (int o = 128; o; o >>= 1) {
        if (t < o) rs[t] = fmaxf(rs[t], rs[t+o]);
        __syncthreads();
    }
    if (t == 0) atomicMax(slot, __float_as_uint(rs[0]));
}

// ---------------- LayerNorm pass 2: recompute y, emit int8 k = clip(round(y/s1)) ----------------
__global__ __launch_bounds__(256) void ln_quant(
    const float* __restrict__ x, const float* __restrict__ g, const float* __restrict__ bia,
    char* __restrict__ yq, const unsigned int* __restrict__ slot)
{
    const int C = 768;
    int row = blockIdx.x, t = threadIdx.x;
    const float* xr = x + (size_t)row * C;
    float v0 = xr[t], v1 = xr[t+256], v2 = xr[t+512];
    __shared__ float rs[256], rss[256];
    rs[t] = v0+v1+v2; rss[t] = v0*v0+v1*v1+v2*v2; __syncthreads();
    for (int o = 128; o; o >>= 1) {
        if (t < o) { rs[t] += rs[t+o]; rss[t] += rss[t+o]; }
        __syncthreads();
    }
    float mean = rs[0] * (1.0f/768.0f);
    float var  = rss[0] * (1.0f/768.0f) - mean*mean;
    float inv  = rsqrtf(var + 1e-6f);
    float s1 = __uint_as_float(*slot) / QMAX + 1e-8f;
    float y0 = (v0-mean)*inv*g[t]     + bia[t];
    float y1 = (v1-mean)*inv*g[t+256] + bia[t+256];
    float y2 = (v2-mean)*inv*g[t+512] + bia[t+512];
    char* yr = yq + (size_t)row * C;
    yr[t]     = (char)(int)fminf(fmaxf(rintf(y0/s1), -QMAX), QMAX);
    yr[t+256] = (char)(int)fminf(fmaxf(rintf(y1/s1), -QMAX), QMAX);
    yr[t+512] = (char)(int)fminf(fmaxf(rintf(y2/s1), -QMAX), QMAX);
}

// ---------------- GEMM: out[m,n] = sA*sW * sum_k kA[m,k]*kW[n,k] + bias[n] ----------------
#define BM 64
#define BN 64
#define BK 16
template<int AMODE>
__global__ __launch_bounds__(256) void gemm_q(
    const void* __restrict__ Aptr, const char* __restrict__ Wq,
    const float* __restrict__ bias, const float* __restrict__ residual,
    void* __restrict__ outp, int M, int N, int K,
    const unsigned int* __restrict__ slotA, float epsA,
    const unsigned int* __restrict__ slotW,
    int apply_gelu, int out_bf16, unsigned int* __restrict__ am_slot)
{
    __shared__ __align__(16) float As[BK][BM];
    __shared__ __align__(16) float Ws[BK][BN];
    __shared__ float sred[256];
    float sA = __uint_as_float(*slotA) / QMAX + epsA;
    float sW = __uint_as_float(*slotW) / QMAX + 1e-8f;
    int t  = threadIdx.x;
    int tx = t & 15;
    int ty = t >> 4;
    int n0 = blockIdx.x * BN;
    int m0 = blockIdx.y * BM;
    int li = t >> 2;              // row in tile [0,64)
    int lj = (t & 3) * 4;         // k-offset {0,4,8,12}
    float acc[4][4] = {};
    for (int k0 = 0; k0 < K; k0 += BK) {
        {
            int gm = m0 + li;
            float a0=0.f, a1=0.f, a2=0.f, a3=0.f;
            if (gm < M) {
                if (AMODE == 0) {
                    char4 v = *reinterpret_cast<const char4*>(
                        (const char*)Aptr + (size_t)gm*K + k0 + lj);
                    a0 = (float)v.x; a1 = (float)v.y; a2 = (float)v.z; a3 = (float)v.w;
                } else {
                    ushort4 u = *reinterpret_cast<const ushort4*>(
                        (const unsigned short*)Aptr + (size_t)gm*K + k0 + lj);
                    a0 = fminf(fmaxf(rintf(bf2f(u.x)/sA), -QMAX), QMAX);
                    a1 = fminf(fmaxf(rintf(bf2f(u.y)/sA), -QMAX), QMAX);
                    a2 = fminf(fmaxf(rintf(bf2f(u.z)/sA), -QMAX), QMAX);
                    a3 = fminf(fmaxf(rintf(bf2f(u.w)/sA), -QMAX), QMAX);
                }
            }
            As[lj+0][li] = a0; As[lj+1][li] = a1; As[lj+2][li] = a2; As[lj+3][li] = a3;
            int gn = n0 + li;
            char4 w = *reinterpret_cast<const char4*>(Wq + (size_t)gn*K + k0 + lj);
            Ws[lj+0][li] = (float)w.x; Ws[lj+1][li] = (float)w.y;
            Ws[lj+2][li] = (float)w.z; Ws[lj+3][li] = (float)w.w;
        }
        __syncthreads();
        #pragma unroll
        for (int kk = 0; kk < BK; ++kk) {
            float4 av = *reinterpret_cast<const float4*>(&As[kk][ty*4]);
            float4 bv = *reinterpret_cast<const float4*>(&Ws[kk][tx*4]);
            float a[4] = {av.x, av.y, av.z, av.w};
            float b[4] = {bv.x, bv.y, bv.z, bv.w};
            #pragma unroll
            for (int i = 0; i < 4; ++i)
                #pragma unroll
                for (int j = 0; j < 4; ++j)
                    acc[i][j] += a[i] * b[j];
        }
        __syncthreads();
    }
    float scale = sA * sW;
    float lmax = 0.f;
    #pragma unroll
    for (int i = 0; i < 4; ++i) {
        int m = m0 + ty*4 + i;
        if (m >= M) continue;
        #pragma unroll
        for (int j = 0; j < 4; ++j) {
            int n = n0 + tx*4 + j;
            float v = scale * acc[i][j] + bias[n];
            if (residual) v += residual[(size_t)m*N + n];
            if (apply_gelu) v = 0.5f * v * (1.0f + erff(v * 0.70710678118654752f));
            if (out_bf16) {
                unsigned short ub = f2bf(v);
                ((unsigned short*)outp)[(size_t)m*N + n] = ub;
                lmax = fmaxf(lmax, fabsf(bf2f(ub)));
            } else {
                ((float*)outp)[(size_t)m*N + n] = v;
                lmax = fmaxf(lmax, fabsf(v));
            }
        }
    }
    if (am_slot) {
        sred[t] = lmax; __syncthreads();
        for (int o = 128; o; o >>= 1) {
            if (t < o) sred[t] = fmaxf(sred[t], sred[t+o]);
            __syncthreads();
        }
        if (t == 0) atomicMax(am_slot, __float_as_uint(sred[0]));
    }
}

// ---------------- tiled attention ----------------
// block = (b, h, 16-query tile), 256 threads (4 waves).
// Phase 1: QK^T into S[16][644] (N padded to 640, -INF beyond 577)
// Phase 2: softmax rows (exp stored back into S, rowsum saved)
// Phase 3: PV with waves partitioning the d-range, acc over all tiles
__global__ __launch_bounds__(256) void attn_tiled(
    const unsigned short* __restrict__ qkv, unsigned short* __restrict__ xa,
    unsigned int* __restrict__ am_slot)
{
    const int Nn = 577;
    const int bh = blockIdx.y;       // b*12 + h
    const int h  = bh % 12;
    const int b  = bh / 12;
    const int q0 = blockIdx.x * 16;
    const int t  = threadIdx.x;

    __shared__ float Qs[16][68];
    __shared__ float KV[64][68];
    __shared__ float S[16][644];
    __shared__ float rowsum[16];
    __shared__ float sred[256];

    const size_t rowstride = 2304;
    const size_t basebh = ((size_t)b * Nn) * rowstride + (size_t)h * 64;

    // ---- stage Q tile (fold 1/sqrt(d) scale) ----
    if (t < 128) {
        int r = t >> 3, e = t & 7;
        int row = q0 + r;
        float f[8];
        if (row < Nn) {
            ushortx8 u = *reinterpret_cast<const ushortx8*>(
                qkv + (size_t)row * rowstride + basebh + e*8);
            #pragma unroll
            for (int i = 0; i < 8; ++i) f[i] = bf2f(u[i]) * 0.125f;
        } else {
            #pragma unroll
            for (int i = 0; i < 8; ++i) f[i] = 0.f;
        }
        *reinterpret_cast<float4*>(&Qs[r][e*8])   = make_float4(f[0],f[1],f[2],f[3]);
        *reinterpret_cast<float4*>(&Qs[r][e*8+4]) = make_float4(f[4],f[5],f[6],f[7]);
    }

    const int g   = t >> 6;         // wave id 0..3
    const int sub = (t >> 4) & 3;   // q sub-index
    const int tx  = t & 15;

    // ---- QK^T ----
    for (int mt = 0; mt < 10; ++mt) {
        __syncthreads();
        #pragma unroll
        for (int pass = 0; pass < 2; ++pass) {
            int r = (t >> 3) + pass*32;
            int e = t & 7;
            int m = mt*64 + r;
            float f[8];
            if (m < Nn) {
                ushortx8 u = *reinterpret_cast<const ushortx8*>(
                    qkv + (size_t)m * rowstride + basebh + 768 + e*8);
                #pragma unroll
                for (int i = 0; i < 8; ++i) f[i] = bf2f(u[i]);
            } else {
                #pragma unroll
                for (int i = 0; i < 8; ++i) f[i] = 0.f;
            }
            *reinterpret_cast<float4*>(&KV[r][e*8])   = make_float4(f[0],f[1],f[2],f[3]);
            *reinterpret_cast<float4*>(&KV[r][e*8+4]) = make_float4(f[4],f[5],f[6],f[7]);
        }
        __syncthreads();
        float acc[4] = {0.f,0.f,0.f,0.f};
        int mloc = g*16 + tx;
        #pragma unroll
        for (int d4 = 0; d4 < 16; ++d4) {
            float4 kvv = *reinterpret_cast<const float4*>(&KV[mloc][d4*4]);
            #pragma unroll
            for (int k = 0; k < 4; ++k) {
                float4 qv = *reinterpret_cast<const float4*>(&Qs[sub+4*k][d4*4]);
                acc[k] += qv.x*kvv.x + qv.y*kvv.y + qv.z*kvv.z + qv.w*kvv.w;
            }
        }
        int m = mt*64 + mloc;
        #pragma unroll
        for (int k = 0; k < 4; ++k)
            S[sub+4*k][m] = (m < Nn) ? acc[k] : -INFINITY;
    }
    __syncthreads();

    // ---- softmax (row = t>>4, 16 lanes each) ----
    {
        int ty = t >> 4;
        float mx = -INFINITY;
        for (int m = tx; m < 640; m += 16) mx = fmaxf(mx, S[ty][m]);
        #pragma unroll
        for (int off = 8; off; off >>= 1) mx = fmaxf(mx, __shfl_xor(mx, off));
        float sum = 0.f;
        for (int m = tx; m < 640; m += 16) {
            float e = expf(S[ty][m] - mx);
            S[ty][m] = e;
            sum += e;
        }
        #pragma unroll
        for (int off = 8; off; off >>= 1) sum += __shfl_xor(sum, off);
        if (tx == 0) rowsum[ty] = sum;
    }

    // ---- PV: wave g owns d-range [g*16, g*16+16) ----
    float acc2[4] = {0.f,0.f,0.f,0.f};
    const int dd = g*16 + tx;
    for (int mt = 0; mt < 10; ++mt) {
        __syncthreads();
        #pragma unroll
        for (int pass = 0; pass < 2; ++pass) {
            int r = (t >> 3) + pass*32;
            int e = t & 7;
            int m = mt*64 + r;
            float f[8];
            if (m < Nn) {
                ushortx8 u = *reinterpret_cast<const ushortx8*>(
                    qkv + (size_t)m * rowstride + basebh + 1536 + e*8);
                #pragma unroll
                for (int i = 0; i < 8; ++i) f[i] = bf2f(u[i]);
            } else {
                #pragma unroll
                for (int i = 0; i < 8; ++i) f[i] = 0.f;
            }
            *reinterpret_cast<float4*>(&KV[r][e*8])   = make_float4(f[0],f[1],f[2],f[3]);
            *reinterpret_cast<float4*>(&KV[r][e*8+4]) = make_float4(f[4],f[5],f[6],f[7]);
        }
        __syncthreads();
        #pragma unroll
        for (int m4 = 0; m4 < 16; ++m4) {
            float4 s4[4];
            #pragma unroll
            for (int k = 0; k < 4; ++k)
                s4[k] = *reinterpret_cast<const float4*>(&S[sub+4*k][mt*64 + m4*4]);
            float v0 = KV[m4*4+0][dd];
            float v1 = KV[m4*4+1][dd];
            float v2 = KV[m4*4+2][dd];
            float v3 = KV[m4*4+3][dd];
            #pragma unroll
            for (int k = 0; k < 4; ++k)
                acc2[k] += s4[k].x*v0 + s4[k].y*v1 + s4[k].z*v2 + s4[k].w*v3;
        }
    }

    // ---- epilogue: divide by rowsum, write bf16, absmax ----
    float lmax = 0.f;
    #pragma unroll
    for (int k = 0; k < 4; ++k) {
        int q = sub + 4*k;
        int row = q0 + q;
        if (row < Nn) {
            float o = acc2[k] / rowsum[q];
            unsigned short ob = f2bf(o);
            xa[((size_t)(b*Nn + row))*768 + h*64 + dd] = ob;
            lmax = fmaxf(lmax, fabsf(bf2f(ob)));
        }
    }
    sred[t] = lmax; __syncthreads();
    for (int o = 128; o; o >>= 1) {
        if (t < o) sred[t] = fmaxf(sred[t], sred[t+o]);
        __syncthreads();
    }
    if (t == 0) atomicMax(am_slot, __float_as_uint(sred[0]));
}

extern "C" void kernel_launch(void* const* d_in, const int* in_sizes, int n_in,
                              void* d_out, int out_size, void* d_ws, size_t ws_size,
                              hipStream_t stream)
{
    const float* x      = (const float*)d_in[0];
    const float* ln1_g  = (const float*)d_in[1];
    const float* ln1_b  = (const float*)d_in[2];
    const float* qkv_w  = (const float*)d_in[3];
    const float* qkv_b  = (const float*)d_in[4];
    const float* proj_w = (const float*)d_in[5];
    const float* proj_b = (const float*)d_in[6];
    const float* ln2_g  = (const float*)d_in[7];
    const float* ln2_b  = (const float*)d_in[8];
    const float* fc1_w  = (const float*)d_in[9];
    const float* fc1_b  = (const float*)d_in[10];
    const float* fc2_w  = (const float*)d_in[11];
    const float* fc2_b  = (const float*)d_in[12];
    float* out = (float*)d_out;

    const int B = 32, Nn = 577, C = 768, H3 = 3072;
    const int M = B * Nn;                   // 18464
    const size_t nA = (size_t)M * C;
    const size_t nQ = (size_t)M * 3 * C;
    const size_t nH = (size_t)M * H3;       // = nQ + nA

    const size_t NEEDED = 256 + 2359296 + nA + 2*nH;   // ~130 MB
    if (ws_size < NEEDED) return;

    char* wsb = (char*)d_ws;
    unsigned int* am = (unsigned int*)wsb;
    char* WQ  = wsb + 256;
    char* XNQ = WQ + 2359296;
    char* BIG = XNQ + nA;
    unsigned short* QKV = (unsigned short*)BIG;
    unsigned short* XA  = (unsigned short*)(BIG + 2*nQ);
    unsigned short* Hbf = (unsigned short*)BIG;

    dim3 blk(256);
    int mblocks = (M + 63) / 64;   // 289

    init_slots<<<dim3(1), dim3(16), 0, stream>>>(am);

    // ---- attention branch ----
    ln_absmax<<<dim3(M), blk, 0, stream>>>(x, ln1_g, ln1_b, am + 0);
    ln_quant <<<dim3(M), blk, 0, stream>>>(x, ln1_g, ln1_b, XNQ, am + 0);

    absmax_f32<<<dim3(1024), blk, 0, stream>>>(qkv_w, (size_t)3*C*C, am + 6);
    quant_w  <<<dim3(1024), blk, 0, stream>>>(qkv_w, WQ, (size_t)3*C*C, am + 6);
    gemm_q<0><<<dim3(3*C/64, mblocks), blk, 0, stream>>>(
        XNQ, WQ, qkv_b, nullptr, QKV, M, 3*C, C,
        am + 0, 2e-8f, am + 6, 0, 1, nullptr);

    attn_tiled<<<dim3(37, 384), blk, 0, stream>>>(QKV, XA, am + 2);

    absmax_f32<<<dim3(1024), blk, 0, stream>>>(proj_w, (size_t)C*C, am + 7);
    quant_w  <<<dim3(1024), blk, 0, stream>>>(proj_w, WQ, (size_t)C*C, am + 7);
    gemm_q<1><<<dim3(C/64, mblocks), blk, 0, stream>>>(
        XA, WQ, proj_b, x, out, M, C, C,
        am + 2, 1e-8f, am + 7, 0, 0, nullptr);          // out = x + proj

    // ---- mlp branch ----
    ln_absmax<<<dim3(M), blk, 0, stream>>>(out, ln2_g, ln2_b, am + 4);
    ln_quant <<<dim3(M), blk, 0, stream>>>(out, ln2_g, ln2_b, XNQ, am + 4);

    absmax_f32<<<dim3(1024), blk, 0, stream>>>(fc1_w, (size_t)H3*C, am + 8);
    quant_w  <<<dim3(1024), blk, 0, stream>>>(fc1_w, WQ, (size_t)H3*C, am + 8);
    gemm_q<0><<<dim3(H3/64, mblocks), blk, 0, stream>>>(
        XNQ, WQ, fc1_b, nullptr, Hbf, M, H3, C,
        am + 4, 2e-8f, am + 8, 1, 1, am + 3);           // gelu, bf16 out, absmax(h)

    absmax_f32<<<dim3(1024), blk, 0, stream>>>(fc2_w, (size_t)C*H3, am + 9);
    quant_w  <<<dim3(1024), blk, 0, stream>>>(fc2_w, WQ, (size_t)C*H3, am + 9);
    gemm_q<1><<<dim3(C/64, mblocks), blk, 0, stream>>>(
        Hbf, WQ, fc2_b, out, out, M, C, H3,
        am + 3, 1e-8f, am + 9, 0, 0, nullptr);          // out += fc2
}

// Round 4
// 2803.610 us; speedup vs baseline: 3.0518x; 1.9022x over previous
//
#include <hip/hip_runtime.h>
#include <hip/hip_bf16.h>
#include <math.h>

#define QMAX 127.0f

// ---- absmax slots (uint-as-float bits) ----
// 0: ln1 y   2: xa(bf16)   3: h(gelu,bf16)   4: ln2 y
// 6: qkv_w   7: proj_w     8: fc1_w          9: fc2_w

typedef unsigned short ushortx8 __attribute__((ext_vector_type(8)));
typedef short bf16x8 __attribute__((ext_vector_type(8)));
typedef float f32x4 __attribute__((ext_vector_type(4)));

__device__ inline float bf2f(unsigned short u) {
    return __uint_as_float(((unsigned int)u) << 16);
}
__device__ inline unsigned short f2bf(float f) {
    __hip_bfloat16 h = __float2bfloat16(f);   // round-to-nearest-even
    return *reinterpret_cast<unsigned short*>(&h);
}

__global__ void init_slots(unsigned int* am) {
    if (threadIdx.x < 16) am[threadIdx.x] = 0u;
}

// ---------------- absmax over fp32 array ----------------
__global__ __launch_bounds__(256) void absmax_f32(
    const float* __restrict__ p, size_t n, unsigned int* __restrict__ slot)
{
    float lmax = 0.f;
    for (size_t i = (size_t)blockIdx.x*256 + threadIdx.x; i < n; i += (size_t)gridDim.x*256)
        lmax = fmaxf(lmax, fabsf(p[i]));
    __shared__ float rs[256];
    int t = threadIdx.x;
    rs[t] = lmax; __syncthreads();
    for (int o = 128; o; o >>= 1) {
        if (t < o) rs[t] = fmaxf(rs[t], rs[t+o]);
        __syncthreads();
    }
    if (t == 0) atomicMax(slot, __float_as_uint(rs[0]));
}

// ---------------- weight quantize: fp32 -> int8 ----------------
__global__ __launch_bounds__(256) void quant_w(
    const float* __restrict__ w, char* __restrict__ q, size_t n,
    const unsigned int* __restrict__ slot)
{
    float s = __uint_as_float(*slot) / QMAX + 1e-8f;
    for (size_t i = (size_t)blockIdx.x*256 + threadIdx.x; i < n; i += (size_t)gridDim.x*256) {
        float k = fminf(fmaxf(rintf(w[i] / s), -QMAX), QMAX);
        q[i] = (char)(int)k;
    }
}

// ---------------- LayerNorm pass 1: absmax(y) only ----------------
__global__ __launch_bounds__(256) void ln_absmax(
    const float* __restrict__ x, const float* __restrict__ g, const float* __restrict__ bia,
    unsigned int* __restrict__ slot)
{
    const int C = 768;
    int row = blockIdx.x, t = threadIdx.x;
    const float* xr = x + (size_t)row * C;
    float v0 = xr[t], v1 = xr[t+256], v2 = xr[t+512];
    __shared__ float rs[256], rss[256];
    rs[t] = v0+v1+v2; rss[t] = v0*v0+v1*v1+v2*v2; __syncthreads();
    for (int o = 128; o; o >>= 1) {
        if (t < o) { rs[t] += rs[t+o]; rss[t] += rss[t+o]; }
        __syncthreads();
    }
    float mean = rs[0] * (1.0f/768.0f);
    float var  = rss[0] * (1.0f/768.0f) - mean*mean;
    float inv  = rsqrtf(var + 1e-6f);
    float y0 = (v0-mean)*inv*g[t]     + bia[t];
    float y1 = (v1-mean)*inv*g[t+256] + bia[t+256];
    float y2 = (v2-mean)*inv*g[t+512] + bia[t+512];
    float lmax = fmaxf(fabsf(y0), fmaxf(fabsf(y1), fabsf(y2)));
    __syncthreads();
    rs[t] = lmax; __syncthreads();
    for (int o = 128; o; o >>= 1) {
        if (t < o) rs[t] = fmaxf(rs[t], rs[t+o]);
        __syncthreads();
    }
    if (t == 0) atomicMax(slot, __float_as_uint(rs[0]));
}

// ---------------- LayerNorm pass 2: recompute y, emit int8 k = clip(round(y/s1)) ----------------
__global__ __launch_bounds__(256) void ln_quant(
    const float* __restrict__ x, const float* __restrict__ g, const float* __restrict__ bia,
    char* __restrict__ yq, const unsigned int* __restrict__ slot)
{
    const int C = 768;
    int row = blockIdx.x, t = threadIdx.x;
    const float* xr = x + (size_t)row * C;
    float v0 = xr[t], v1 = xr[t+256], v2 = xr[t+512];
    __shared__ float rs[256], rss[256];
    rs[t] = v0+v1+v2; rss[t] = v0*v0+v1*v1+v2*v2; __syncthreads();
    for (int o = 128; o; o >>= 1) {
        if (t < o) { rs[t] += rs[t+o]; rss[t] += rss[t+o]; }
        __syncthreads();
    }
    float mean = rs[0] * (1.0f/768.0f);
    float var  = rss[0] * (1.0f/768.0f) - mean*mean;
    float inv  = rsqrtf(var + 1e-6f);
    float s1 = __uint_as_float(*slot) / QMAX + 1e-8f;
    float y0 = (v0-mean)*inv*g[t]     + bia[t];
    float y1 = (v1-mean)*inv*g[t+256] + bia[t+256];
    float y2 = (v2-mean)*inv*g[t+512] + bia[t+512];
    char* yr = yq + (size_t)row * C;
    yr[t]     = (char)(int)fminf(fmaxf(rintf(y0/s1), -QMAX), QMAX);
    yr[t+256] = (char)(int)fminf(fmaxf(rintf(y1/s1), -QMAX), QMAX);
    yr[t+512] = (char)(int)fminf(fmaxf(rintf(y2/s1), -QMAX), QMAX);
}

// ---------------- MFMA GEMM: out[m,n] = sA*sW * sum_k kA[m,k]*kW[n,k] + bias[n] ----------------
// Operands are int-valued (|k|<=127): exact in bf16; fp32 accum exact (<2^24).
// AMODE 0: A int8.  AMODE 1: A bf16, quantized on the fly (k = clip(rint(v*rsA))).
// 128x128 tile, BK=64, 4 waves each 64x64 via 4x4 frags of mfma_f32_16x16x32_bf16.
template<int AMODE>
__global__ __launch_bounds__(256) void gemm_mfma(
    const void* __restrict__ Aptr, const char* __restrict__ Wq,
    const float* __restrict__ bias, const float* __restrict__ residual,
    void* __restrict__ outp, int M, int N, int K,
    const unsigned int* __restrict__ slotA, float epsA,
    const unsigned int* __restrict__ slotW,
    int apply_gelu, int out_bf16, unsigned int* __restrict__ am_slot)
{
    __shared__ __align__(16) unsigned short As[128][72];   // +8 pad: 144B row stride
    __shared__ __align__(16) unsigned short Ws[128][72];
    __shared__ float sred[256];

    float sA  = __uint_as_float(*slotA) / QMAX + epsA;
    float sW  = __uint_as_float(*slotW) / QMAX + 1e-8f;
    float rsA = 1.0f / sA;

    const int t    = threadIdx.x;
    const int lane = t & 63;
    const int w    = t >> 6;        // wave 0..3
    const int wr   = w >> 1;        // wave row 0..1
    const int wc   = w & 1;         // wave col 0..1
    const int lr   = lane & 15;     // fragment row/col index
    const int lk   = lane >> 4;     // k-octet 0..3
    const int m0   = blockIdx.y * 128;
    const int n0   = blockIdx.x * 128;

    f32x4 acc[4][4];
    #pragma unroll
    for (int i = 0; i < 4; ++i)
        #pragma unroll
        for (int j = 0; j < 4; ++j)
            acc[i][j] = (f32x4){0.f,0.f,0.f,0.f};

    for (int kt = 0; kt < K; kt += 64) {
        __syncthreads();   // LDS reuse from previous compute
        // ---- stage A tile (128x64): 4 segments of 8 per thread ----
        #pragma unroll
        for (int i = 0; i < 4; ++i) {
            int s   = t + 256*i;
            int row = s >> 3;
            int c8  = (s & 7) * 8;
            int gm  = m0 + row;
            ushortx8 vv;
            if (AMODE == 0) {
                if (gm < M) {
                    int2 q8 = *reinterpret_cast<const int2*>(
                        (const char*)Aptr + (size_t)gm*K + kt + c8);
                    #pragma unroll
                    for (int j = 0; j < 4; ++j)
                        vv[j] = f2bf((float)(signed char)(q8.x >> (8*j)));
                    #pragma unroll
                    for (int j = 0; j < 4; ++j)
                        vv[4+j] = f2bf((float)(signed char)(q8.y >> (8*j)));
                } else {
                    #pragma unroll
                    for (int j = 0; j < 8; ++j) vv[j] = 0;
                }
            } else {
                if (gm < M) {
                    ushortx8 u = *reinterpret_cast<const ushortx8*>(
                        (const unsigned short*)Aptr + (size_t)gm*K + kt + c8);
                    #pragma unroll
                    for (int j = 0; j < 8; ++j) {
                        float k = fminf(fmaxf(rintf(bf2f(u[j]) * rsA), -QMAX), QMAX);
                        vv[j] = f2bf(k);
                    }
                } else {
                    #pragma unroll
                    for (int j = 0; j < 8; ++j) vv[j] = 0;
                }
            }
            *reinterpret_cast<ushortx8*>(&As[row][c8]) = vv;
        }
        // ---- stage W tile (128x64), N % 128 == 0 ----
        #pragma unroll
        for (int i = 0; i < 4; ++i) {
            int s   = t + 256*i;
            int row = s >> 3;
            int c8  = (s & 7) * 8;
            int2 q8 = *reinterpret_cast<const int2*>(
                Wq + (size_t)(n0 + row)*K + kt + c8);
            ushortx8 vv;
            #pragma unroll
            for (int j = 0; j < 4; ++j)
                vv[j] = f2bf((float)(signed char)(q8.x >> (8*j)));
            #pragma unroll
            for (int j = 0; j < 4; ++j)
                vv[4+j] = f2bf((float)(signed char)(q8.y >> (8*j)));
            *reinterpret_cast<ushortx8*>(&Ws[row][c8]) = vv;
        }
        __syncthreads();
        // ---- compute: 2 k-halves x 16 fragment-pairs ----
        #pragma unroll
        for (int kk = 0; kk < 2; ++kk) {
            bf16x8 af[4], bf[4];
            #pragma unroll
            for (int mi = 0; mi < 4; ++mi)
                af[mi] = *reinterpret_cast<const bf16x8*>(
                    &As[wr*64 + mi*16 + lr][kk*32 + lk*8]);
            #pragma unroll
            for (int ni = 0; ni < 4; ++ni)
                bf[ni] = *reinterpret_cast<const bf16x8*>(
                    &Ws[wc*64 + ni*16 + lr][kk*32 + lk*8]);
            #pragma unroll
            for (int mi = 0; mi < 4; ++mi)
                #pragma unroll
                for (int ni = 0; ni < 4; ++ni)
                    acc[mi][ni] = __builtin_amdgcn_mfma_f32_16x16x32_bf16(
                        af[mi], bf[ni], acc[mi][ni], 0, 0, 0);
        }
    }

    // ---- epilogue: C/D map col=lane&15, row=(lane>>4)*4+reg ----
    float scale = sA * sW;
    float lmax = 0.f;
    #pragma unroll
    for (int mi = 0; mi < 4; ++mi) {
        #pragma unroll
        for (int j = 0; j < 4; ++j) {
            int m = m0 + wr*64 + mi*16 + lk*4 + j;
            if (m >= M) continue;
            #pragma unroll
            for (int ni = 0; ni < 4; ++ni) {
                int n = n0 + wc*64 + ni*16 + lr;
                float v = scale * acc[mi][ni][j] + bias[n];
                if (residual) v += residual[(size_t)m*N + n];
                if (apply_gelu) v = 0.5f * v * (1.0f + erff(v * 0.70710678118654752f));
                if (out_bf16) {
                    unsigned short ub = f2bf(v);
                    ((unsigned short*)outp)[(size_t)m*N + n] = ub;
                    lmax = fmaxf(lmax, fabsf(bf2f(ub)));
                } else {
                    ((float*)outp)[(size_t)m*N + n] = v;
                    lmax = fmaxf(lmax, fabsf(v));
                }
            }
        }
    }
    if (am_slot) {
        sred[t] = lmax; __syncthreads();
        for (int o = 128; o; o >>= 1) {
            if (t < o) sred[t] = fmaxf(sred[t], sred[t+o]);
            __syncthreads();
        }
        if (t == 0) atomicMax(am_slot, __float_as_uint(sred[0]));
    }
}

// ---------------- tiled attention (unchanged from R3) ----------------
__global__ __launch_bounds__(256) void attn_tiled(
    const unsigned short* __restrict__ qkv, unsigned short* __restrict__ xa,
    unsigned int* __restrict__ am_slot)
{
    const int Nn = 577;
    const int bh = blockIdx.y;
    const int h  = bh % 12;
    const int b  = bh / 12;
    const int q0 = blockIdx.x * 16;
    const int t  = threadIdx.x;

    __shared__ float Qs[16][68];
    __shared__ float KV[64][68];
    __shared__ float S[16][644];
    __shared__ float rowsum[16];
    __shared__ float sred[256];

    const size_t rowstride = 2304;
    const size_t basebh = ((size_t)b * Nn) * rowstride + (size_t)h * 64;

    if (t < 128) {
        int r = t >> 3, e = t & 7;
        int row = q0 + r;
        float f[8];
        if (row < Nn) {
            ushortx8 u = *reinterpret_cast<const ushortx8*>(
                qkv + (size_t)row * rowstride + basebh + e*8);
            #pragma unroll
            for (int i = 0; i < 8; ++i) f[i] = bf2f(u[i]) * 0.125f;
        } else {
            #pragma unroll
            for (int i = 0; i < 8; ++i) f[i] = 0.f;
        }
        *reinterpret_cast<float4*>(&Qs[r][e*8])   = make_float4(f[0],f[1],f[2],f[3]);
        *reinterpret_cast<float4*>(&Qs[r][e*8+4]) = make_float4(f[4],f[5],f[6],f[7]);
    }

    const int g   = t >> 6;
    const int sub = (t >> 4) & 3;
    const int tx  = t & 15;

    for (int mt = 0; mt < 10; ++mt) {
        __syncthreads();
        #pragma unroll
        for (int pass = 0; pass < 2; ++pass) {
            int r = (t >> 3) + pass*32;
            int e = t & 7;
            int m = mt*64 + r;
            float f[8];
            if (m < Nn) {
                ushortx8 u = *reinterpret_cast<const ushortx8*>(
                    qkv + (size_t)m * rowstride + basebh + 768 + e*8);
                #pragma unroll
                for (int i = 0; i < 8; ++i) f[i] = bf2f(u[i]);
            } else {
                #pragma unroll
                for (int i = 0; i < 8; ++i) f[i] = 0.f;
            }
            *reinterpret_cast<float4*>(&KV[r][e*8])   = make_float4(f[0],f[1],f[2],f[3]);
            *reinterpret_cast<float4*>(&KV[r][e*8+4]) = make_float4(f[4],f[5],f[6],f[7]);
        }
        __syncthreads();
        float acc[4] = {0.f,0.f,0.f,0.f};
        int mloc = g*16 + tx;
        #pragma unroll
        for (int d4 = 0; d4 < 16; ++d4) {
            float4 kvv = *reinterpret_cast<const float4*>(&KV[mloc][d4*4]);
            #pragma unroll
            for (int k = 0; k < 4; ++k) {
                float4 qv = *reinterpret_cast<const float4*>(&Qs[sub+4*k][d4*4]);
                acc[k] += qv.x*kvv.x + qv.y*kvv.y + qv.z*kvv.z + qv.w*kvv.w;
            }
        }
        int m = mt*64 + mloc;
        #pragma unroll
        for (int k = 0; k < 4; ++k)
            S[sub+4*k][m] = (m < Nn) ? acc[k] : -INFINITY;
    }
    __syncthreads();

    {
        int ty = t >> 4;
        float mx = -INFINITY;
        for (int m = tx; m < 640; m += 16) mx = fmaxf(mx, S[ty][m]);
        #pragma unroll
        for (int off = 8; off; off >>= 1) mx = fmaxf(mx, __shfl_xor(mx, off));
        float sum = 0.f;
        for (int m = tx; m < 640; m += 16) {
            float e = expf(S[ty][m] - mx);
            S[ty][m] = e;
            sum += e;
        }
        #pragma unroll
        for (int off = 8; off; off >>= 1) sum += __shfl_xor(sum, off);
        if (tx == 0) rowsum[ty] = sum;
    }

    float acc2[4] = {0.f,0.f,0.f,0.f};
    const int dd = g*16 + tx;
    for (int mt = 0; mt < 10; ++mt) {
        __syncthreads();
        #pragma unroll
        for (int pass = 0; pass < 2; ++pass) {
            int r = (t >> 3) + pass*32;
            int e = t & 7;
            int m = mt*64 + r;
            float f[8];
            if (m < Nn) {
                ushortx8 u = *reinterpret_cast<const ushortx8*>(
                    qkv + (size_t)m * rowstride + basebh + 1536 + e*8);
                #pragma unroll
                for (int i = 0; i < 8; ++i) f[i] = bf2f(u[i]);
            } else {
                #pragma unroll
                for (int i = 0; i < 8; ++i) f[i] = 0.f;
            }
            *reinterpret_cast<float4*>(&KV[r][e*8])   = make_float4(f[0],f[1],f[2],f[3]);
            *reinterpret_cast<float4*>(&KV[r][e*8+4]) = make_float4(f[4],f[5],f[6],f[7]);
        }
        __syncthreads();
        #pragma unroll
        for (int m4 = 0; m4 < 16; ++m4) {
            float4 s4[4];
            #pragma unroll
            for (int k = 0; k < 4; ++k)
                s4[k] = *reinterpret_cast<const float4*>(&S[sub+4*k][mt*64 + m4*4]);
            float v0 = KV[m4*4+0][dd];
            float v1 = KV[m4*4+1][dd];
            float v2 = KV[m4*4+2][dd];
            float v3 = KV[m4*4+3][dd];
            #pragma unroll
            for (int k = 0; k < 4; ++k)
                acc2[k] += s4[k].x*v0 + s4[k].y*v1 + s4[k].z*v2 + s4[k].w*v3;
        }
    }

    float lmax = 0.f;
    #pragma unroll
    for (int k = 0; k < 4; ++k) {
        int q = sub + 4*k;
        int row = q0 + q;
        if (row < Nn) {
            float o = acc2[k] / rowsum[q];
            unsigned short ob = f2bf(o);
            xa[((size_t)(b*Nn + row))*768 + h*64 + dd] = ob;
            lmax = fmaxf(lmax, fabsf(bf2f(ob)));
        }
    }
    sred[t] = lmax; __syncthreads();
    for (int o = 128; o; o >>= 1) {
        if (t < o) sred[t] = fmaxf(sred[t], sred[t+o]);
        __syncthreads();
    }
    if (t == 0) atomicMax(am_slot, __float_as_uint(sred[0]));
}

extern "C" void kernel_launch(void* const* d_in, const int* in_sizes, int n_in,
                              void* d_out, int out_size, void* d_ws, size_t ws_size,
                              hipStream_t stream)
{
    const float* x      = (const float*)d_in[0];
    const float* ln1_g  = (const float*)d_in[1];
    const float* ln1_b  = (const float*)d_in[2];
    const float* qkv_w  = (const float*)d_in[3];
    const float* qkv_b  = (const float*)d_in[4];
    const float* proj_w = (const float*)d_in[5];
    const float* proj_b = (const float*)d_in[6];
    const float* ln2_g  = (const float*)d_in[7];
    const float* ln2_b  = (const float*)d_in[8];
    const float* fc1_w  = (const float*)d_in[9];
    const float* fc1_b  = (const float*)d_in[10];
    const float* fc2_w  = (const float*)d_in[11];
    const float* fc2_b  = (const float*)d_in[12];
    float* out = (float*)d_out;

    const int B = 32, Nn = 577, C = 768, H3 = 3072;
    const int M = B * Nn;                   // 18464
    const size_t nA = (size_t)M * C;
    const size_t nQ = (size_t)M * 3 * C;
    const size_t nH = (size_t)M * H3;       // = nQ + nA

    const size_t NEEDED = 256 + 2359296 + nA + 2*nH;   // ~130 MB (proven fit)
    if (ws_size < NEEDED) return;

    char* wsb = (char*)d_ws;
    unsigned int* am = (unsigned int*)wsb;
    char* WQ  = wsb + 256;
    char* XNQ = WQ + 2359296;
    char* BIG = XNQ + nA;
    unsigned short* QKV = (unsigned short*)BIG;
    unsigned short* XA  = (unsigned short*)(BIG + 2*nQ);
    unsigned short* Hbf = (unsigned short*)BIG;

    dim3 blk(256);
    int mt128 = (M + 127) / 128;   // 145

    init_slots<<<dim3(1), dim3(16), 0, stream>>>(am);

    // ---- attention branch ----
    ln_absmax<<<dim3(M), blk, 0, stream>>>(x, ln1_g, ln1_b, am + 0);
    ln_quant <<<dim3(M), blk, 0, stream>>>(x, ln1_g, ln1_b, XNQ, am + 0);

    absmax_f32<<<dim3(1024), blk, 0, stream>>>(qkv_w, (size_t)3*C*C, am + 6);
    quant_w  <<<dim3(1024), blk, 0, stream>>>(qkv_w, WQ, (size_t)3*C*C, am + 6);
    gemm_mfma<0><<<dim3(3*C/128, mt128), blk, 0, stream>>>(
        XNQ, WQ, qkv_b, nullptr, QKV, M, 3*C, C,
        am + 0, 2e-8f, am + 6, 0, 1, nullptr);

    attn_tiled<<<dim3(37, 384), blk, 0, stream>>>(QKV, XA, am + 2);

    absmax_f32<<<dim3(1024), blk, 0, stream>>>(proj_w, (size_t)C*C, am + 7);
    quant_w  <<<dim3(1024), blk, 0, stream>>>(proj_w, WQ, (size_t)C*C, am + 7);
    gemm_mfma<1><<<dim3(C/128, mt128), blk, 0, stream>>>(
        XA, WQ, proj_b, x, out, M, C, C,
        am + 2, 1e-8f, am + 7, 0, 0, nullptr);          // out = x + proj

    // ---- mlp branch ----
    ln_absmax<<<dim3(M), blk, 0, stream>>>(out, ln2_g, ln2_b, am + 4);
    ln_quant <<<dim3(M), blk, 0, stream>>>(out, ln2_g, ln2_b, XNQ, am + 4);

    absmax_f32<<<dim3(1024), blk, 0, stream>>>(fc1_w, (size_t)H3*C, am + 8);
    quant_w  <<<dim3(1024), blk, 0, stream>>>(fc1_w, WQ, (size_t)H3*C, am + 8);
    gemm_mfma<0><<<dim3(H3/128, mt128), blk, 0, stream>>>(
        XNQ, WQ, fc1_b, nullptr, Hbf, M, H3, C,
        am + 4, 2e-8f, am + 8, 1, 1, am + 3);           // gelu, bf16 out, absmax(h)

    absmax_f32<<<dim3(1024), blk, 0, stream>>>(fc2_w, (size_t)C*H3, am + 9);
    quant_w  <<<dim3(1024), blk, 0, stream>>>(fc2_w, WQ, (size_t)C*H3, am + 9);
    gemm_mfma<1><<<dim3(C/128, mt128), blk, 0, stream>>>(
        Hbf, WQ, fc2_b, out, out, M, C, H3,
        am + 3, 1e-8f, am + 9, 0, 0, nullptr);          // out += fc2
}

// Round 5
// 1571.424 us; speedup vs baseline: 5.4448x; 1.7841x over previous
//
#include <hip/hip_runtime.h>
#include <hip/hip_bf16.h>
#include <math.h>

#define QMAX 127.0f

// ---- absmax slots (uint-as-float bits) ----
// 0: ln1 y   2: xa(bf16)   3: h(gelu,bf16)   4: ln2 y
// 6: qkv_w   7: proj_w     8: fc1_w          9: fc2_w

typedef unsigned short ushortx8 __attribute__((ext_vector_type(8)));
typedef short bf16x8 __attribute__((ext_vector_type(8)));
typedef float f32x4 __attribute__((ext_vector_type(4)));

__device__ inline float bf2f(unsigned short u) {
    return __uint_as_float(((unsigned int)u) << 16);
}
__device__ inline unsigned short f2bf(float f) {
    __hip_bfloat16 h = __float2bfloat16(f);   // round-to-nearest-even
    return *reinterpret_cast<unsigned short*>(&h);
}

__global__ void init_slots(unsigned int* am) {
    if (threadIdx.x < 16) am[threadIdx.x] = 0u;
}

// ---------------- absmax over fp32 array ----------------
__global__ __launch_bounds__(256) void absmax_f32(
    const float* __restrict__ p, size_t n, unsigned int* __restrict__ slot)
{
    float lmax = 0.f;
    for (size_t i = (size_t)blockIdx.x*256 + threadIdx.x; i < n; i += (size_t)gridDim.x*256)
        lmax = fmaxf(lmax, fabsf(p[i]));
    __shared__ float rs[256];
    int t = threadIdx.x;
    rs[t] = lmax; __syncthreads();
    for (int o = 128; o; o >>= 1) {
        if (t < o) rs[t] = fmaxf(rs[t], rs[t+o]);
        __syncthreads();
    }
    if (t == 0) atomicMax(slot, __float_as_uint(rs[0]));
}

// ---------------- weight quantize: fp32 -> int8 ----------------
__global__ __launch_bounds__(256) void quant_w(
    const float* __restrict__ w, char* __restrict__ q, size_t n,
    const unsigned int* __restrict__ slot)
{
    float s = __uint_as_float(*slot) / QMAX + 1e-8f;
    for (size_t i = (size_t)blockIdx.x*256 + threadIdx.x; i < n; i += (size_t)gridDim.x*256) {
        float k = fminf(fmaxf(rintf(w[i] / s), -QMAX), QMAX);
        q[i] = (char)(int)k;
    }
}

// ---------------- LayerNorm pass 1: absmax(y) only ----------------
__global__ __launch_bounds__(256) void ln_absmax(
    const float* __restrict__ x, const float* __restrict__ g, const float* __restrict__ bia,
    unsigned int* __restrict__ slot)
{
    const int C = 768;
    int row = blockIdx.x, t = threadIdx.x;
    const float* xr = x + (size_t)row * C;
    float v0 = xr[t], v1 = xr[t+256], v2 = xr[t+512];
    __shared__ float rs[256], rss[256];
    rs[t] = v0+v1+v2; rss[t] = v0*v0+v1*v1+v2*v2; __syncthreads();
    for (int o = 128; o; o >>= 1) {
        if (t < o) { rs[t] += rs[t+o]; rss[t] += rss[t+o]; }
        __syncthreads();
    }
    float mean = rs[0] * (1.0f/768.0f);
    float var  = rss[0] * (1.0f/768.0f) - mean*mean;
    float inv  = rsqrtf(var + 1e-6f);
    float y0 = (v0-mean)*inv*g[t]     + bia[t];
    float y1 = (v1-mean)*inv*g[t+256] + bia[t+256];
    float y2 = (v2-mean)*inv*g[t+512] + bia[t+512];
    float lmax = fmaxf(fabsf(y0), fmaxf(fabsf(y1), fabsf(y2)));
    __syncthreads();
    rs[t] = lmax; __syncthreads();
    for (int o = 128; o; o >>= 1) {
        if (t < o) rs[t] = fmaxf(rs[t], rs[t+o]);
        __syncthreads();
    }
    if (t == 0) atomicMax(slot, __float_as_uint(rs[0]));
}

// ---------------- LayerNorm pass 2: recompute y, emit int8 k = clip(round(y/s1)) ----------------
__global__ __launch_bounds__(256) void ln_quant(
    const float* __restrict__ x, const float* __restrict__ g, const float* __restrict__ bia,
    char* __restrict__ yq, const unsigned int* __restrict__ slot)
{
    const int C = 768;
    int row = blockIdx.x, t = threadIdx.x;
    const float* xr = x + (size_t)row * C;
    float v0 = xr[t], v1 = xr[t+256], v2 = xr[t+512];
    __shared__ float rs[256], rss[256];
    rs[t] = v0+v1+v2; rss[t] = v0*v0+v1*v1+v2*v2; __syncthreads();
    for (int o = 128; o; o >>= 1) {
        if (t < o) { rs[t] += rs[t+o]; rss[t] += rss[t+o]; }
        __syncthreads();
    }
    float mean = rs[0] * (1.0f/768.0f);
    float var  = rss[0] * (1.0f/768.0f) - mean*mean;
    float inv  = rsqrtf(var + 1e-6f);
    float s1 = __uint_as_float(*slot) / QMAX + 1e-8f;
    float y0 = (v0-mean)*inv*g[t]     + bia[t];
    float y1 = (v1-mean)*inv*g[t+256] + bia[t+256];
    float y2 = (v2-mean)*inv*g[t+512] + bia[t+512];
    char* yr = yq + (size_t)row * C;
    yr[t]     = (char)(int)fminf(fmaxf(rintf(y0/s1), -QMAX), QMAX);
    yr[t+256] = (char)(int)fminf(fmaxf(rintf(y1/s1), -QMAX), QMAX);
    yr[t+512] = (char)(int)fminf(fmaxf(rintf(y2/s1), -QMAX), QMAX);
}

// ---------------- MFMA GEMM (unchanged from R4) ----------------
template<int AMODE>
__global__ __launch_bounds__(256) void gemm_mfma(
    const void* __restrict__ Aptr, const char* __restrict__ Wq,
    const float* __restrict__ bias, const float* __restrict__ residual,
    void* __restrict__ outp, int M, int N, int K,
    const unsigned int* __restrict__ slotA, float epsA,
    const unsigned int* __restrict__ slotW,
    int apply_gelu, int out_bf16, unsigned int* __restrict__ am_slot)
{
    __shared__ __align__(16) unsigned short As[128][72];
    __shared__ __align__(16) unsigned short Ws[128][72];
    __shared__ float sred[256];

    float sA  = __uint_as_float(*slotA) / QMAX + epsA;
    float sW  = __uint_as_float(*slotW) / QMAX + 1e-8f;
    float rsA = 1.0f / sA;

    const int t    = threadIdx.x;
    const int lane = t & 63;
    const int w    = t >> 6;
    const int wr   = w >> 1;
    const int wc   = w & 1;
    const int lr   = lane & 15;
    const int lk   = lane >> 4;
    const int m0   = blockIdx.y * 128;
    const int n0   = blockIdx.x * 128;

    f32x4 acc[4][4];
    #pragma unroll
    for (int i = 0; i < 4; ++i)
        #pragma unroll
        for (int j = 0; j < 4; ++j)
            acc[i][j] = (f32x4){0.f,0.f,0.f,0.f};

    for (int kt = 0; kt < K; kt += 64) {
        __syncthreads();
        #pragma unroll
        for (int i = 0; i < 4; ++i) {
            int s   = t + 256*i;
            int row = s >> 3;
            int c8  = (s & 7) * 8;
            int gm  = m0 + row;
            ushortx8 vv;
            if (AMODE == 0) {
                if (gm < M) {
                    int2 q8 = *reinterpret_cast<const int2*>(
                        (const char*)Aptr + (size_t)gm*K + kt + c8);
                    #pragma unroll
                    for (int j = 0; j < 4; ++j)
                        vv[j] = f2bf((float)(signed char)(q8.x >> (8*j)));
                    #pragma unroll
                    for (int j = 0; j < 4; ++j)
                        vv[4+j] = f2bf((float)(signed char)(q8.y >> (8*j)));
                } else {
                    #pragma unroll
                    for (int j = 0; j < 8; ++j) vv[j] = 0;
                }
            } else {
                if (gm < M) {
                    ushortx8 u = *reinterpret_cast<const ushortx8*>(
                        (const unsigned short*)Aptr + (size_t)gm*K + kt + c8);
                    #pragma unroll
                    for (int j = 0; j < 8; ++j) {
                        float k = fminf(fmaxf(rintf(bf2f(u[j]) * rsA), -QMAX), QMAX);
                        vv[j] = f2bf(k);
                    }
                } else {
                    #pragma unroll
                    for (int j = 0; j < 8; ++j) vv[j] = 0;
                }
            }
            *reinterpret_cast<ushortx8*>(&As[row][c8]) = vv;
        }
        #pragma unroll
        for (int i = 0; i < 4; ++i) {
            int s   = t + 256*i;
            int row = s >> 3;
            int c8  = (s & 7) * 8;
            int2 q8 = *reinterpret_cast<const int2*>(
                Wq + (size_t)(n0 + row)*K + kt + c8);
            ushortx8 vv;
            #pragma unroll
            for (int j = 0; j < 4; ++j)
                vv[j] = f2bf((float)(signed char)(q8.x >> (8*j)));
            #pragma unroll
            for (int j = 0; j < 4; ++j)
                vv[4+j] = f2bf((float)(signed char)(q8.y >> (8*j)));
            *reinterpret_cast<ushortx8*>(&Ws[row][c8]) = vv;
        }
        __syncthreads();
        #pragma unroll
        for (int kk = 0; kk < 2; ++kk) {
            bf16x8 af[4], bf[4];
            #pragma unroll
            for (int mi = 0; mi < 4; ++mi)
                af[mi] = *reinterpret_cast<const bf16x8*>(
                    &As[wr*64 + mi*16 + lr][kk*32 + lk*8]);
            #pragma unroll
            for (int ni = 0; ni < 4; ++ni)
                bf[ni] = *reinterpret_cast<const bf16x8*>(
                    &Ws[wc*64 + ni*16 + lr][kk*32 + lk*8]);
            #pragma unroll
            for (int mi = 0; mi < 4; ++mi)
                #pragma unroll
                for (int ni = 0; ni < 4; ++ni)
                    acc[mi][ni] = __builtin_amdgcn_mfma_f32_16x16x32_bf16(
                        af[mi], bf[ni], acc[mi][ni], 0, 0, 0);
        }
    }

    float scale = sA * sW;
    float lmax = 0.f;
    #pragma unroll
    for (int mi = 0; mi < 4; ++mi) {
        #pragma unroll
        for (int j = 0; j < 4; ++j) {
            int m = m0 + wr*64 + mi*16 + lk*4 + j;
            if (m >= M) continue;
            #pragma unroll
            for (int ni = 0; ni < 4; ++ni) {
                int n = n0 + wc*64 + ni*16 + lr;
                float v = scale * acc[mi][ni][j] + bias[n];
                if (residual) v += residual[(size_t)m*N + n];
                if (apply_gelu) v = 0.5f * v * (1.0f + erff(v * 0.70710678118654752f));
                if (out_bf16) {
                    unsigned short ub = f2bf(v);
                    ((unsigned short*)outp)[(size_t)m*N + n] = ub;
                    lmax = fmaxf(lmax, fabsf(bf2f(ub)));
                } else {
                    ((float*)outp)[(size_t)m*N + n] = v;
                    lmax = fmaxf(lmax, fabsf(v));
                }
            }
        }
    }
    if (am_slot) {
        sred[t] = lmax; __syncthreads();
        for (int o = 128; o; o >>= 1) {
            if (t < o) sred[t] = fmaxf(sred[t], sred[t+o]);
            __syncthreads();
        }
        if (t == 0) atomicMax(am_slot, __float_as_uint(sred[0]));
    }
}

// ---------------- MFMA flash attention ----------------
// block = (b, h, 64-query tile), 4 waves; wave w owns queries [q0+w*16, +16).
// K/V tiles of 64 keys; online softmax in registers; P via bf16 LDS round-trip;
// V staged transposed so PV B-fragments are contiguous ds_read_b128.
__global__ __launch_bounds__(256) void attn_mfma(
    const unsigned short* __restrict__ qkv, unsigned short* __restrict__ xa,
    unsigned int* __restrict__ am_slot)
{
    const int Nn = 577;
    const int bh = blockIdx.y;
    const int h  = bh % 12;
    const int b  = bh / 12;
    const int q0 = blockIdx.x * 64;
    const int t  = threadIdx.x;
    const int w    = t >> 6;
    const int lane = t & 63;
    const int lr   = lane & 15;
    const int lk   = lane >> 4;

    __shared__ __align__(16) unsigned short Ks[64][72];
    __shared__ __align__(16) unsigned short Vt[64][72];
    __shared__ __align__(16) unsigned short Pw[4][16][72];
    __shared__ float sred[256];

    const size_t rowstride = 2304;
    const size_t basebh = ((size_t)b * Nn) * rowstride + (size_t)h * 64;

    // ---- Q fragments in registers (A operand; m = q0+w*16+lr, k = d) ----
    bf16x8 qf[2];
    {
        int row = q0 + w*16 + lr;
        if (row < Nn) {
            const unsigned short* qrow = qkv + (size_t)row * rowstride + basebh;
            qf[0] = *reinterpret_cast<const bf16x8*>(qrow + lk*8);
            qf[1] = *reinterpret_cast<const bf16x8*>(qrow + 32 + lk*8);
        } else {
            #pragma unroll
            for (int j = 0; j < 8; ++j) { qf[0][j] = 0; qf[1][j] = 0; }
        }
    }

    float m_run[4], l_run[4];
    f32x4 acc_o[4];
    #pragma unroll
    for (int j = 0; j < 4; ++j) { m_run[j] = -INFINITY; l_run[j] = 0.f; }
    #pragma unroll
    for (int df = 0; df < 4; ++df) acc_o[df] = (f32x4){0.f,0.f,0.f,0.f};

    for (int kt = 0; kt < 10; ++kt) {
        __syncthreads();   // previous PV done before overwriting Ks/Vt
        // ---- stage K tile + V tile (transposed) ----
        #pragma unroll
        for (int pass = 0; pass < 2; ++pass) {
            int r   = (t >> 3) + pass*32;
            int e8  = (t & 7) * 8;
            int key = kt*64 + r;
            ushortx8 ku, vu;
            if (key < Nn) {
                const unsigned short* krow = qkv + (size_t)key * rowstride + basebh;
                ku = *reinterpret_cast<const ushortx8*>(krow + 768  + e8);
                vu = *reinterpret_cast<const ushortx8*>(krow + 1536 + e8);
            } else {
                #pragma unroll
                for (int j = 0; j < 8; ++j) { ku[j] = 0; vu[j] = 0; }
            }
            *reinterpret_cast<ushortx8*>(&Ks[r][e8]) = ku;
            #pragma unroll
            for (int j = 0; j < 8; ++j) Vt[e8 + j][r] = vu[j];
        }
        __syncthreads();

        // ---- QK^T: S[16 m][64 n] per wave ----
        f32x4 s[4];
        #pragma unroll
        for (int nf = 0; nf < 4; ++nf) s[nf] = (f32x4){0.f,0.f,0.f,0.f};
        #pragma unroll
        for (int kk = 0; kk < 2; ++kk) {
            #pragma unroll
            for (int nf = 0; nf < 4; ++nf) {
                bf16x8 kfrag = *reinterpret_cast<const bf16x8*>(
                    &Ks[nf*16 + lr][kk*32 + lk*8]);
                s[nf] = __builtin_amdgcn_mfma_f32_16x16x32_bf16(
                    qf[kk], kfrag, s[nf], 0, 0, 0);
            }
        }
        // scale + key mask (col = key = kt*64+nf*16+lr, same for all j)
        #pragma unroll
        for (int nf = 0; nf < 4; ++nf) {
            int key = kt*64 + nf*16 + lr;
            bool valid = key < Nn;
            #pragma unroll
            for (int j = 0; j < 4; ++j)
                s[nf][j] = valid ? s[nf][j] * 0.125f : -INFINITY;
        }

        // ---- online softmax (rows m = lk*4+j, across 16-lane group) ----
        float tmax[4];
        #pragma unroll
        for (int j = 0; j < 4; ++j)
            tmax[j] = fmaxf(fmaxf(s[0][j], s[1][j]), fmaxf(s[2][j], s[3][j]));
        #pragma unroll
        for (int off = 1; off <= 8; off <<= 1)
            #pragma unroll
            for (int j = 0; j < 4; ++j)
                tmax[j] = fmaxf(tmax[j], __shfl_xor(tmax[j], off));
        float fac[4];
        #pragma unroll
        for (int j = 0; j < 4; ++j) {
            float nm = fmaxf(m_run[j], tmax[j]);
            fac[j] = __expf(m_run[j] - nm);
            m_run[j] = nm;
        }
        float psum[4] = {0.f,0.f,0.f,0.f};
        #pragma unroll
        for (int nf = 0; nf < 4; ++nf)
            #pragma unroll
            for (int j = 0; j < 4; ++j) {
                float p = __expf(s[nf][j] - m_run[j]);
                s[nf][j] = p;
                psum[j] += p;
            }
        #pragma unroll
        for (int off = 1; off <= 8; off <<= 1)
            #pragma unroll
            for (int j = 0; j < 4; ++j)
                psum[j] += __shfl_xor(psum[j], off);
        #pragma unroll
        for (int j = 0; j < 4; ++j)
            l_run[j] = l_run[j] * fac[j] + psum[j];
        #pragma unroll
        for (int df = 0; df < 4; ++df)
            #pragma unroll
            for (int j = 0; j < 4; ++j)
                acc_o[df][j] *= fac[j];

        // ---- P -> bf16 LDS (element (m=lk*4+j, n=nf*16+lr)) ----
        #pragma unroll
        for (int nf = 0; nf < 4; ++nf)
            #pragma unroll
            for (int j = 0; j < 4; ++j)
                Pw[w][lk*4 + j][nf*16 + lr] = f2bf(s[nf][j]);
        __syncthreads();

        // ---- PV: O[16 m][64 d] += P * V ----
        #pragma unroll
        for (int kk = 0; kk < 2; ++kk) {
            bf16x8 pf = *reinterpret_cast<const bf16x8*>(
                &Pw[w][lr][kk*32 + lk*8]);
            #pragma unroll
            for (int df = 0; df < 4; ++df) {
                bf16x8 vf = *reinterpret_cast<const bf16x8*>(
                    &Vt[df*16 + lr][kk*32 + lk*8]);
                acc_o[df] = __builtin_amdgcn_mfma_f32_16x16x32_bf16(
                    pf, vf, acc_o[df], 0, 0, 0);
            }
        }
    }

    // ---- epilogue: divide by l, store bf16, absmax ----
    float lmax = 0.f;
    #pragma unroll
    for (int j = 0; j < 4; ++j) {
        int m = q0 + w*16 + lk*4 + j;
        if (m < Nn) {
            float rl = 1.0f / l_run[j];
            #pragma unroll
            for (int df = 0; df < 4; ++df) {
                int d = df*16 + lr;
                float o = acc_o[df][j] * rl;
                unsigned short ob = f2bf(o);
                xa[((size_t)(b*Nn + m))*768 + h*64 + d] = ob;
                lmax = fmaxf(lmax, fabsf(bf2f(ob)));
            }
        }
    }
    sred[t] = lmax; __syncthreads();
    for (int o = 128; o; o >>= 1) {
        if (t < o) sred[t] = fmaxf(sred[t], sred[t+o]);
        __syncthreads();
    }
    if (t == 0) atomicMax(am_slot, __float_as_uint(sred[0]));
}

extern "C" void kernel_launch(void* const* d_in, const int* in_sizes, int n_in,
                              void* d_out, int out_size, void* d_ws, size_t ws_size,
                              hipStream_t stream)
{
    const float* x      = (const float*)d_in[0];
    const float* ln1_g  = (const float*)d_in[1];
    const float* ln1_b  = (const float*)d_in[2];
    const float* qkv_w  = (const float*)d_in[3];
    const float* qkv_b  = (const float*)d_in[4];
    const float* proj_w = (const float*)d_in[5];
    const float* proj_b = (const float*)d_in[6];
    const float* ln2_g  = (const float*)d_in[7];
    const float* ln2_b  = (const float*)d_in[8];
    const float* fc1_w  = (const float*)d_in[9];
    const float* fc1_b  = (const float*)d_in[10];
    const float* fc2_w  = (const float*)d_in[11];
    const float* fc2_b  = (const float*)d_in[12];
    float* out = (float*)d_out;

    const int B = 32, Nn = 577, C = 768, H3 = 3072;
    const int M = B * Nn;
    const size_t nA = (size_t)M * C;
    const size_t nQ = (size_t)M * 3 * C;
    const size_t nH = (size_t)M * H3;

    const size_t NEEDED = 256 + 2359296 + nA + 2*nH;
    if (ws_size < NEEDED) return;

    char* wsb = (char*)d_ws;
    unsigned int* am = (unsigned int*)wsb;
    char* WQ  = wsb + 256;
    char* XNQ = WQ + 2359296;
    char* BIG = XNQ + nA;
    unsigned short* QKV = (unsigned short*)BIG;
    unsigned short* XA  = (unsigned short*)(BIG + 2*nQ);
    unsigned short* Hbf = (unsigned short*)BIG;

    dim3 blk(256);
    int mt128 = (M + 127) / 128;

    init_slots<<<dim3(1), dim3(16), 0, stream>>>(am);

    // ---- attention branch ----
    ln_absmax<<<dim3(M), blk, 0, stream>>>(x, ln1_g, ln1_b, am + 0);
    ln_quant <<<dim3(M), blk, 0, stream>>>(x, ln1_g, ln1_b, XNQ, am + 0);

    absmax_f32<<<dim3(1024), blk, 0, stream>>>(qkv_w, (size_t)3*C*C, am + 6);
    quant_w  <<<dim3(1024), blk, 0, stream>>>(qkv_w, WQ, (size_t)3*C*C, am + 6);
    gemm_mfma<0><<<dim3(3*C/128, mt128), blk, 0, stream>>>(
        XNQ, WQ, qkv_b, nullptr, QKV, M, 3*C, C,
        am + 0, 2e-8f, am + 6, 0, 1, nullptr);

    attn_mfma<<<dim3(10, 384), blk, 0, stream>>>(QKV, XA, am + 2);

    absmax_f32<<<dim3(1024), blk, 0, stream>>>(proj_w, (size_t)C*C, am + 7);
    quant_w  <<<dim3(1024), blk, 0, stream>>>(proj_w, WQ, (size_t)C*C, am + 7);
    gemm_mfma<1><<<dim3(C/128, mt128), blk, 0, stream>>>(
        XA, WQ, proj_b, x, out, M, C, C,
        am + 2, 1e-8f, am + 7, 0, 0, nullptr);

    // ---- mlp branch ----
    ln_absmax<<<dim3(M), blk, 0, stream>>>(out, ln2_g, ln2_b, am + 4);
    ln_quant <<<dim3(M), blk, 0, stream>>>(out, ln2_g, ln2_b, XNQ, am + 4);

    absmax_f32<<<dim3(1024), blk, 0, stream>>>(fc1_w, (size_t)H3*C, am + 8);
    quant_w  <<<dim3(1024), blk, 0, stream>>>(fc1_w, WQ, (size_t)H3*C, am + 8);
    gemm_mfma<0><<<dim3(H3/128, mt128), blk, 0, stream>>>(
        XNQ, WQ, fc1_b, nullptr, Hbf, M, H3, C,
        am + 4, 2e-8f, am + 8, 1, 1, am + 3);

    absmax_f32<<<dim3(1024), blk, 0, stream>>>(fc2_w, (size_t)C*H3, am + 9);
    quant_w  <<<dim3(1024), blk, 0, stream>>>(fc2_w, WQ, (size_t)C*H3, am + 9);
    gemm_mfma<1><<<dim3(C/128, mt128), blk, 0, stream>>>(
        Hbf, WQ, fc2_b, out, out, M, C, H3,
        am + 3, 1e-8f, am + 9, 0, 0, nullptr);
}

// Round 6
// 1324.623 us; speedup vs baseline: 6.4592x; 1.1863x over previous
//
#include <hip/hip_runtime.h>
#include <hip/hip_bf16.h>
#include <math.h>

#define QMAX 127.0f

// ---- absmax slots (uint-as-float bits) ----
// 0: ln1 y   2: xa(bf16)   3: h(gelu,bf16)   4: ln2 y
// 6: qkv_w   7: proj_w     8: fc1_w          9: fc2_w

typedef unsigned short ushortx8 __attribute__((ext_vector_type(8)));
typedef short bf16x8 __attribute__((ext_vector_type(8)));
typedef float f32x4 __attribute__((ext_vector_type(4)));
typedef int int32x4 __attribute__((ext_vector_type(4)));

__device__ inline float bf2f(unsigned short u) {
    return __uint_as_float(((unsigned int)u) << 16);
}
__device__ inline unsigned short f2bf(float f) {
    __hip_bfloat16 h = __float2bfloat16(f);   // round-to-nearest-even
    return *reinterpret_cast<unsigned short*>(&h);
}

__global__ void init_slots(unsigned int* am) {
    if (threadIdx.x < 16) am[threadIdx.x] = 0u;
}

// ---------------- absmax over fp32 array ----------------
__global__ __launch_bounds__(256) void absmax_f32(
    const float* __restrict__ p, size_t n, unsigned int* __restrict__ slot)
{
    float lmax = 0.f;
    for (size_t i = (size_t)blockIdx.x*256 + threadIdx.x; i < n; i += (size_t)gridDim.x*256)
        lmax = fmaxf(lmax, fabsf(p[i]));
    __shared__ float rs[256];
    int t = threadIdx.x;
    rs[t] = lmax; __syncthreads();
    for (int o = 128; o; o >>= 1) {
        if (t < o) rs[t] = fmaxf(rs[t], rs[t+o]);
        __syncthreads();
    }
    if (t == 0) atomicMax(slot, __float_as_uint(rs[0]));
}

// ---------------- weight quantize: fp32 -> int8 ----------------
__global__ __launch_bounds__(256) void quant_w(
    const float* __restrict__ w, char* __restrict__ q, size_t n,
    const unsigned int* __restrict__ slot)
{
    float s = __uint_as_float(*slot) / QMAX + 1e-8f;
    for (size_t i = (size_t)blockIdx.x*256 + threadIdx.x; i < n; i += (size_t)gridDim.x*256) {
        float k = fminf(fmaxf(rintf(w[i] / s), -QMAX), QMAX);
        q[i] = (char)(int)k;
    }
}

// ---------------- LayerNorm pass 1: absmax(y) only ----------------
__global__ __launch_bounds__(256) void ln_absmax(
    const float* __restrict__ x, const float* __restrict__ g, const float* __restrict__ bia,
    unsigned int* __restrict__ slot)
{
    const int C = 768;
    int row = blockIdx.x, t = threadIdx.x;
    const float* xr = x + (size_t)row * C;
    float v0 = xr[t], v1 = xr[t+256], v2 = xr[t+512];
    __shared__ float rs[256], rss[256];
    rs[t] = v0+v1+v2; rss[t] = v0*v0+v1*v1+v2*v2; __syncthreads();
    for (int o = 128; o; o >>= 1) {
        if (t < o) { rs[t] += rs[t+o]; rss[t] += rss[t+o]; }
        __syncthreads();
    }
    float mean = rs[0] * (1.0f/768.0f);
    float var  = rss[0] * (1.0f/768.0f) - mean*mean;
    float inv  = rsqrtf(var + 1e-6f);
    float y0 = (v0-mean)*inv*g[t]     + bia[t];
    float y1 = (v1-mean)*inv*g[t+256] + bia[t+256];
    float y2 = (v2-mean)*inv*g[t+512] + bia[t+512];
    float lmax = fmaxf(fabsf(y0), fmaxf(fabsf(y1), fabsf(y2)));
    __syncthreads();
    rs[t] = lmax; __syncthreads();
    for (int o = 128; o; o >>= 1) {
        if (t < o) rs[t] = fmaxf(rs[t], rs[t+o]);
        __syncthreads();
    }
    if (t == 0) atomicMax(slot, __float_as_uint(rs[0]));
}

// ---------------- LayerNorm pass 2: recompute y, emit int8 k = clip(round(y/s1)) ----------------
__global__ __launch_bounds__(256) void ln_quant(
    const float* __restrict__ x, const float* __restrict__ g, const float* __restrict__ bia,
    char* __restrict__ yq, const unsigned int* __restrict__ slot)
{
    const int C = 768;
    int row = blockIdx.x, t = threadIdx.x;
    const float* xr = x + (size_t)row * C;
    float v0 = xr[t], v1 = xr[t+256], v2 = xr[t+512];
    __shared__ float rs[256], rss[256];
    rs[t] = v0+v1+v2; rss[t] = v0*v0+v1*v1+v2*v2; __syncthreads();
    for (int o = 128; o; o >>= 1) {
        if (t < o) { rs[t] += rs[t+o]; rss[t] += rss[t+o]; }
        __syncthreads();
    }
    float mean = rs[0] * (1.0f/768.0f);
    float var  = rss[0] * (1.0f/768.0f) - mean*mean;
    float inv  = rsqrtf(var + 1e-6f);
    float s1 = __uint_as_float(*slot) / QMAX + 1e-8f;
    float y0 = (v0-mean)*inv*g[t]     + bia[t];
    float y1 = (v1-mean)*inv*g[t+256] + bia[t+256];
    float y2 = (v2-mean)*inv*g[t+512] + bia[t+512];
    char* yr = yq + (size_t)row * C;
    yr[t]     = (char)(int)fminf(fmaxf(rintf(y0/s1), -QMAX), QMAX);
    yr[t+256] = (char)(int)fminf(fmaxf(rintf(y1/s1), -QMAX), QMAX);
    yr[t+512] = (char)(int)fminf(fmaxf(rintf(y2/s1), -QMAX), QMAX);
}

// ---------------- int8 MFMA GEMM: out[m,n] = sA*sW * sum_k kA[m,k]*kW[n,k] + bias[n] ----------------
// i32 accumulation of int8 products is exact; float(acc) exact (<2^24).
// AMODE 0: A int8. AMODE 1: A bf16, quantized+packed during staging.
// 128x128 tile, BK=128, 4 waves each 64x64 via 4x4 frags of mfma_i32_16x16x64_i8.
template<int AMODE>
__global__ __launch_bounds__(256) void gemm_i8(
    const void* __restrict__ Aptr, const char* __restrict__ Wq,
    const float* __restrict__ bias, const float* __restrict__ residual,
    void* __restrict__ outp, int M, int N, int K,
    const unsigned int* __restrict__ slotA, float epsA,
    const unsigned int* __restrict__ slotW,
    int apply_gelu, int out_bf16, unsigned int* __restrict__ am_slot)
{
    __shared__ __align__(16) char As[128][144];   // 144B stride: 16B-aligned, ~2-way banks
    __shared__ __align__(16) char Ws[128][144];
    __shared__ float sred[256];

    float sA  = __uint_as_float(*slotA) / QMAX + epsA;
    float sW  = __uint_as_float(*slotW) / QMAX + 1e-8f;
    float rsA = 1.0f / sA;

    const int t    = threadIdx.x;
    const int lane = t & 63;
    const int w    = t >> 6;
    const int wr   = w >> 1;
    const int wc   = w & 1;
    const int lr   = lane & 15;
    const int lk   = lane >> 4;
    const int m0   = blockIdx.y * 128;
    const int n0   = blockIdx.x * 128;

    int32x4 acc[4][4];
    #pragma unroll
    for (int i = 0; i < 4; ++i)
        #pragma unroll
        for (int j = 0; j < 4; ++j)
            acc[i][j] = (int32x4){0,0,0,0};

    for (int kt = 0; kt < K; kt += 128) {
        __syncthreads();
        // ---- stage A tile (128 rows x 128 int8): 4 chunks of 16B per thread ----
        #pragma unroll
        for (int i = 0; i < 4; ++i) {
            int chunk = t + 256*i;           // 0..1023
            int row   = chunk >> 3;
            int c16   = (chunk & 7) * 16;
            int gm    = m0 + row;
            int32x4 vv = (int32x4){0,0,0,0};
            if (AMODE == 0) {
                if (gm < M)
                    vv = *reinterpret_cast<const int32x4*>(
                        (const char*)Aptr + (size_t)gm*K + kt + c16);
            } else {
                if (gm < M) {
                    const unsigned short* ap =
                        (const unsigned short*)Aptr + (size_t)gm*K + kt + c16;
                    ushortx8 u0 = *reinterpret_cast<const ushortx8*>(ap);
                    ushortx8 u1 = *reinterpret_cast<const ushortx8*>(ap + 8);
                    #pragma unroll
                    for (int q = 0; q < 4; ++q) {
                        int dw = 0;
                        #pragma unroll
                        for (int j = 0; j < 4; ++j) {
                            int e = q*4 + j;
                            float f = bf2f(e < 8 ? u0[e] : u1[e-8]);
                            int k = (int)fminf(fmaxf(rintf(f * rsA), -QMAX), QMAX);
                            dw |= (k & 0xff) << (8*j);
                        }
                        vv[q] = dw;
                    }
                }
            }
            *reinterpret_cast<int32x4*>(&As[row][c16]) = vv;
        }
        // ---- stage W tile (128 x 128 int8), N % 128 == 0 ----
        #pragma unroll
        for (int i = 0; i < 4; ++i) {
            int chunk = t + 256*i;
            int row   = chunk >> 3;
            int c16   = (chunk & 7) * 16;
            int32x4 vv = *reinterpret_cast<const int32x4*>(
                Wq + (size_t)(n0 + row)*K + kt + c16);
            *reinterpret_cast<int32x4*>(&Ws[row][c16]) = vv;
        }
        __syncthreads();
        // ---- compute: 2 k-steps of K=64 ----
        #pragma unroll
        for (int ks = 0; ks < 2; ++ks) {
            int32x4 af[4], bf[4];
            #pragma unroll
            for (int mi = 0; mi < 4; ++mi)
                af[mi] = *reinterpret_cast<const int32x4*>(
                    &As[wr*64 + mi*16 + lr][ks*64 + lk*16]);
            #pragma unroll
            for (int ni = 0; ni < 4; ++ni)
                bf[ni] = *reinterpret_cast<const int32x4*>(
                    &Ws[wc*64 + ni*16 + lr][ks*64 + lk*16]);
            #pragma unroll
            for (int mi = 0; mi < 4; ++mi)
                #pragma unroll
                for (int ni = 0; ni < 4; ++ni)
                    acc[mi][ni] = __builtin_amdgcn_mfma_i32_16x16x64_i8(
                        af[mi], bf[ni], acc[mi][ni], 0, 0, 0);
        }
    }

    // ---- epilogue: C/D map col=lane&15, row=(lane>>4)*4+reg ----
    float scale = sA * sW;
    float lmax = 0.f;
    #pragma unroll
    for (int mi = 0; mi < 4; ++mi) {
        #pragma unroll
        for (int j = 0; j < 4; ++j) {
            int m = m0 + wr*64 + mi*16 + lk*4 + j;
            if (m >= M) continue;
            #pragma unroll
            for (int ni = 0; ni < 4; ++ni) {
                int n = n0 + wc*64 + ni*16 + lr;
                float v = scale * (float)acc[mi][ni][j] + bias[n];
                if (residual) v += residual[(size_t)m*N + n];
                if (apply_gelu) v = 0.5f * v * (1.0f + erff(v * 0.70710678118654752f));
                if (out_bf16) {
                    unsigned short ub = f2bf(v);
                    ((unsigned short*)outp)[(size_t)m*N + n] = ub;
                    lmax = fmaxf(lmax, fabsf(bf2f(ub)));
                } else {
                    ((float*)outp)[(size_t)m*N + n] = v;
                    lmax = fmaxf(lmax, fabsf(v));
                }
            }
        }
    }
    if (am_slot) {
        sred[t] = lmax; __syncthreads();
        for (int o = 128; o; o >>= 1) {
            if (t < o) sred[t] = fmaxf(sred[t], sred[t+o]);
            __syncthreads();
        }
        if (t == 0) atomicMax(am_slot, __float_as_uint(sred[0]));
    }
}

// ---------------- MFMA flash attention (unchanged from R5) ----------------
__global__ __launch_bounds__(256) void attn_mfma(
    const unsigned short* __restrict__ qkv, unsigned short* __restrict__ xa,
    unsigned int* __restrict__ am_slot)
{
    const int Nn = 577;
    const int bh = blockIdx.y;
    const int h  = bh % 12;
    const int b  = bh / 12;
    const int q0 = blockIdx.x * 64;
    const int t  = threadIdx.x;
    const int w    = t >> 6;
    const int lane = t & 63;
    const int lr   = lane & 15;
    const int lk   = lane >> 4;

    __shared__ __align__(16) unsigned short Ks[64][72];
    __shared__ __align__(16) unsigned short Vt[64][72];
    __shared__ __align__(16) unsigned short Pw[4][16][72];
    __shared__ float sred[256];

    const size_t rowstride = 2304;
    const size_t basebh = ((size_t)b * Nn) * rowstride + (size_t)h * 64;

    bf16x8 qf[2];
    {
        int row = q0 + w*16 + lr;
        if (row < Nn) {
            const unsigned short* qrow = qkv + (size_t)row * rowstride + basebh;
            qf[0] = *reinterpret_cast<const bf16x8*>(qrow + lk*8);
            qf[1] = *reinterpret_cast<const bf16x8*>(qrow + 32 + lk*8);
        } else {
            #pragma unroll
            for (int j = 0; j < 8; ++j) { qf[0][j] = 0; qf[1][j] = 0; }
        }
    }

    float m_run[4], l_run[4];
    f32x4 acc_o[4];
    #pragma unroll
    for (int j = 0; j < 4; ++j) { m_run[j] = -INFINITY; l_run[j] = 0.f; }
    #pragma unroll
    for (int df = 0; df < 4; ++df) acc_o[df] = (f32x4){0.f,0.f,0.f,0.f};

    for (int kt = 0; kt < 10; ++kt) {
        __syncthreads();
        #pragma unroll
        for (int pass = 0; pass < 2; ++pass) {
            int r   = (t >> 3) + pass*32;
            int e8  = (t & 7) * 8;
            int key = kt*64 + r;
            ushortx8 ku, vu;
            if (key < Nn) {
                const unsigned short* krow = qkv + (size_t)key * rowstride + basebh;
                ku = *reinterpret_cast<const ushortx8*>(krow + 768  + e8);
                vu = *reinterpret_cast<const ushortx8*>(krow + 1536 + e8);
            } else {
                #pragma unroll
                for (int j = 0; j < 8; ++j) { ku[j] = 0; vu[j] = 0; }
            }
            *reinterpret_cast<ushortx8*>(&Ks[r][e8]) = ku;
            #pragma unroll
            for (int j = 0; j < 8; ++j) Vt[e8 + j][r] = vu[j];
        }
        __syncthreads();

        f32x4 s[4];
        #pragma unroll
        for (int nf = 0; nf < 4; ++nf) s[nf] = (f32x4){0.f,0.f,0.f,0.f};
        #pragma unroll
        for (int kk = 0; kk < 2; ++kk) {
            #pragma unroll
            for (int nf = 0; nf < 4; ++nf) {
                bf16x8 kfrag = *reinterpret_cast<const bf16x8*>(
                    &Ks[nf*16 + lr][kk*32 + lk*8]);
                s[nf] = __builtin_amdgcn_mfma_f32_16x16x32_bf16(
                    qf[kk], kfrag, s[nf], 0, 0, 0);
            }
        }
        #pragma unroll
        for (int nf = 0; nf < 4; ++nf) {
            int key = kt*64 + nf*16 + lr;
            bool valid = key < Nn;
            #pragma unroll
            for (int j = 0; j < 4; ++j)
                s[nf][j] = valid ? s[nf][j] * 0.125f : -INFINITY;
        }

        float tmax[4];
        #pragma unroll
        for (int j = 0; j < 4; ++j)
            tmax[j] = fmaxf(fmaxf(s[0][j], s[1][j]), fmaxf(s[2][j], s[3][j]));
        #pragma unroll
        for (int off = 1; off <= 8; off <<= 1)
            #pragma unroll
            for (int j = 0; j < 4; ++j)
                tmax[j] = fmaxf(tmax[j], __shfl_xor(tmax[j], off));
        float fac[4];
        #pragma unroll
        for (int j = 0; j < 4; ++j) {
            float nm = fmaxf(m_run[j], tmax[j]);
            fac[j] = __expf(m_run[j] - nm);
            m_run[j] = nm;
        }
        float psum[4] = {0.f,0.f,0.f,0.f};
        #pragma unroll
        for (int nf = 0; nf < 4; ++nf)
            #pragma unroll
            for (int j = 0; j < 4; ++j) {
                float p = __expf(s[nf][j] - m_run[j]);
                s[nf][j] = p;
                psum[j] += p;
            }
        #pragma unroll
        for (int off = 1; off <= 8; off <<= 1)
            #pragma unroll
            for (int j = 0; j < 4; ++j)
                psum[j] += __shfl_xor(psum[j], off);
        #pragma unroll
        for (int j = 0; j < 4; ++j)
            l_run[j] = l_run[j] * fac[j] + psum[j];
        #pragma unroll
        for (int df = 0; df < 4; ++df)
            #pragma unroll
            for (int j = 0; j < 4; ++j)
                acc_o[df][j] *= fac[j];

        #pragma unroll
        for (int nf = 0; nf < 4; ++nf)
            #pragma unroll
            for (int j = 0; j < 4; ++j)
                Pw[w][lk*4 + j][nf*16 + lr] = f2bf(s[nf][j]);
        __syncthreads();

        #pragma unroll
        for (int kk = 0; kk < 2; ++kk) {
            bf16x8 pf = *reinterpret_cast<const bf16x8*>(
                &Pw[w][lr][kk*32 + lk*8]);
            #pragma unroll
            for (int df = 0; df < 4; ++df) {
                bf16x8 vf = *reinterpret_cast<const bf16x8*>(
                    &Vt[df*16 + lr][kk*32 + lk*8]);
                acc_o[df] = __builtin_amdgcn_mfma_f32_16x16x32_bf16(
                    pf, vf, acc_o[df], 0, 0, 0);
            }
        }
    }

    float lmax = 0.f;
    #pragma unroll
    for (int j = 0; j < 4; ++j) {
        int m = q0 + w*16 + lk*4 + j;
        if (m < Nn) {
            float rl = 1.0f / l_run[j];
            #pragma unroll
            for (int df = 0; df < 4; ++df) {
                int d = df*16 + lr;
                float o = acc_o[df][j] * rl;
                unsigned short ob = f2bf(o);
                xa[((size_t)(b*Nn + m))*768 + h*64 + d] = ob;
                lmax = fmaxf(lmax, fabsf(bf2f(ob)));
            }
        }
    }
    sred[t] = lmax; __syncthreads();
    for (int o = 128; o; o >>= 1) {
        if (t < o) sred[t] = fmaxf(sred[t], sred[t+o]);
        __syncthreads();
    }
    if (t == 0) atomicMax(am_slot, __float_as_uint(sred[0]));
}

extern "C" void kernel_launch(void* const* d_in, const int* in_sizes, int n_in,
                              void* d_out, int out_size, void* d_ws, size_t ws_size,
                              hipStream_t stream)
{
    const float* x      = (const float*)d_in[0];
    const float* ln1_g  = (const float*)d_in[1];
    const float* ln1_b  = (const float*)d_in[2];
    const float* qkv_w  = (const float*)d_in[3];
    const float* qkv_b  = (const float*)d_in[4];
    const float* proj_w = (const float*)d_in[5];
    const float* proj_b = (const float*)d_in[6];
    const float* ln2_g  = (const float*)d_in[7];
    const float* ln2_b  = (const float*)d_in[8];
    const float* fc1_w  = (const float*)d_in[9];
    const float* fc1_b  = (const float*)d_in[10];
    const float* fc2_w  = (const float*)d_in[11];
    const float* fc2_b  = (const float*)d_in[12];
    float* out = (float*)d_out;

    const int B = 32, Nn = 577, C = 768, H3 = 3072;
    const int M = B * Nn;
    const size_t nA = (size_t)M * C;
    const size_t nQ = (size_t)M * 3 * C;
    const size_t nH = (size_t)M * H3;

    const size_t NEEDED = 256 + 2359296 + nA + 2*nH;
    if (ws_size < NEEDED) return;

    char* wsb = (char*)d_ws;
    unsigned int* am = (unsigned int*)wsb;
    char* WQ  = wsb + 256;
    char* XNQ = WQ + 2359296;
    char* BIG = XNQ + nA;
    unsigned short* QKV = (unsigned short*)BIG;
    unsigned short* XA  = (unsigned short*)(BIG + 2*nQ);
    unsigned short* Hbf = (unsigned short*)BIG;

    dim3 blk(256);
    int mt128 = (M + 127) / 128;

    init_slots<<<dim3(1), dim3(16), 0, stream>>>(am);

    // ---- attention branch ----
    ln_absmax<<<dim3(M), blk, 0, stream>>>(x, ln1_g, ln1_b, am + 0);
    ln_quant <<<dim3(M), blk, 0, stream>>>(x, ln1_g, ln1_b, XNQ, am + 0);

    absmax_f32<<<dim3(1024), blk, 0, stream>>>(qkv_w, (size_t)3*C*C, am + 6);
    quant_w  <<<dim3(1024), blk, 0, stream>>>(qkv_w, WQ, (size_t)3*C*C, am + 6);
    gemm_i8<0><<<dim3(3*C/128, mt128), blk, 0, stream>>>(
        XNQ, WQ, qkv_b, nullptr, QKV, M, 3*C, C,
        am + 0, 2e-8f, am + 6, 0, 1, nullptr);

    attn_mfma<<<dim3(10, 384), blk, 0, stream>>>(QKV, XA, am + 2);

    absmax_f32<<<dim3(1024), blk, 0, stream>>>(proj_w, (size_t)C*C, am + 7);
    quant_w  <<<dim3(1024), blk, 0, stream>>>(proj_w, WQ, (size_t)C*C, am + 7);
    gemm_i8<1><<<dim3(C/128, mt128), blk, 0, stream>>>(
        XA, WQ, proj_b, x, out, M, C, C,
        am + 2, 1e-8f, am + 7, 0, 0, nullptr);

    // ---- mlp branch ----
    ln_absmax<<<dim3(M), blk, 0, stream>>>(out, ln2_g, ln2_b, am + 4);
    ln_quant <<<dim3(M), blk, 0, stream>>>(out, ln2_g, ln2_b, XNQ, am + 4);

    absmax_f32<<<dim3(1024), blk, 0, stream>>>(fc1_w, (size_t)H3*C, am + 8);
    quant_w  <<<dim3(1024), blk, 0, stream>>>(fc1_w, WQ, (size_t)H3*C, am + 8);
    gemm_i8<0><<<dim3(H3/128, mt128), blk, 0, stream>>>(
        XNQ, WQ, fc1_b, nullptr, Hbf, M, H3, C,
        am + 4, 2e-8f, am + 8, 1, 1, am + 3);

    absmax_f32<<<dim3(1024), blk, 0, stream>>>(fc2_w, (size_t)C*H3, am + 9);
    quant_w  <<<dim3(1024), blk, 0, stream>>>(fc2_w, WQ, (size_t)C*H3, am + 9);
    gemm_i8<1><<<dim3(C/128, mt128), blk, 0, stream>>>(
        Hbf, WQ, fc2_b, out, out, M, C, H3,
        am + 3, 1e-8f, am + 9, 0, 0, nullptr);
}

// Round 7
// 1297.849 us; speedup vs baseline: 6.5925x; 1.0206x over previous
//
#include <hip/hip_runtime.h>
#include <hip/hip_bf16.h>
#include <math.h>

#define QMAX 127.0f

// ---- absmax slots (uint-as-float bits) ----
// 0: ln1 y   2: xa(bf16)   3: h(gelu,bf16)   4: ln2 y
// 6: qkv_w   7: proj_w     8: fc1_w          9: fc2_w

typedef unsigned short ushortx8 __attribute__((ext_vector_type(8)));
typedef short bf16x8 __attribute__((ext_vector_type(8)));
typedef float f32x4 __attribute__((ext_vector_type(4)));
typedef int int32x4 __attribute__((ext_vector_type(4)));

__device__ inline float bf2f(unsigned short u) {
    return __uint_as_float(((unsigned int)u) << 16);
}
__device__ inline unsigned short f2bf(float f) {
    __hip_bfloat16 h = __float2bfloat16(f);   // round-to-nearest-even
    return *reinterpret_cast<unsigned short*>(&h);
}

__global__ void init_slots(unsigned int* am) {
    if (threadIdx.x < 16) am[threadIdx.x] = 0u;
}

// ---------------- absmax over fp32 array ----------------
__global__ __launch_bounds__(256) void absmax_f32(
    const float* __restrict__ p, size_t n, unsigned int* __restrict__ slot)
{
    float lmax = 0.f;
    for (size_t i = (size_t)blockIdx.x*256 + threadIdx.x; i < n; i += (size_t)gridDim.x*256)
        lmax = fmaxf(lmax, fabsf(p[i]));
    __shared__ float rs[256];
    int t = threadIdx.x;
    rs[t] = lmax; __syncthreads();
    for (int o = 128; o; o >>= 1) {
        if (t < o) rs[t] = fmaxf(rs[t], rs[t+o]);
        __syncthreads();
    }
    if (t == 0) atomicMax(slot, __float_as_uint(rs[0]));
}

// ---------------- weight quantize: fp32 -> int8 ----------------
__global__ __launch_bounds__(256) void quant_w(
    const float* __restrict__ w, char* __restrict__ q, size_t n,
    const unsigned int* __restrict__ slot)
{
    float s = __uint_as_float(*slot) / QMAX + 1e-8f;
    for (size_t i = (size_t)blockIdx.x*256 + threadIdx.x; i < n; i += (size_t)gridDim.x*256) {
        float k = fminf(fmaxf(rintf(w[i] / s), -QMAX), QMAX);
        q[i] = (char)(int)k;
    }
}

// ---------------- activation quantize: bf16 -> int8 (8 elems/thread/iter) ----------------
__global__ __launch_bounds__(256) void quant_bf2i8(
    const unsigned short* __restrict__ src, char* __restrict__ dst, size_t n8,
    const unsigned int* __restrict__ slot)
{
    float s  = __uint_as_float(*slot) / QMAX + 1e-8f;
    float rs = 1.0f / s;
    for (size_t i = (size_t)blockIdx.x*256 + threadIdx.x; i < n8; i += (size_t)gridDim.x*256) {
        ushortx8 u = *reinterpret_cast<const ushortx8*>(src + i*8);
        int lo = 0, hi = 0;
        #pragma unroll
        for (int j = 0; j < 4; ++j) {
            int k = (int)fminf(fmaxf(rintf(bf2f(u[j]) * rs), -QMAX), QMAX);
            lo |= (k & 0xff) << (8*j);
        }
        #pragma unroll
        for (int j = 0; j < 4; ++j) {
            int k = (int)fminf(fmaxf(rintf(bf2f(u[4+j]) * rs), -QMAX), QMAX);
            hi |= (k & 0xff) << (8*j);
        }
        reinterpret_cast<int2*>(dst)[i] = make_int2(lo, hi);
    }
}

// ---------------- LayerNorm pass 1: absmax(y) only ----------------
__global__ __launch_bounds__(256) void ln_absmax(
    const float* __restrict__ x, const float* __restrict__ g, const float* __restrict__ bia,
    unsigned int* __restrict__ slot)
{
    const int C = 768;
    int row = blockIdx.x, t = threadIdx.x;
    const float* xr = x + (size_t)row * C;
    float v0 = xr[t], v1 = xr[t+256], v2 = xr[t+512];
    __shared__ float rs[256], rss[256];
    rs[t] = v0+v1+v2; rss[t] = v0*v0+v1*v1+v2*v2; __syncthreads();
    for (int o = 128; o; o >>= 1) {
        if (t < o) { rs[t] += rs[t+o]; rss[t] += rss[t+o]; }
        __syncthreads();
    }
    float mean = rs[0] * (1.0f/768.0f);
    float var  = rss[0] * (1.0f/768.0f) - mean*mean;
    float inv  = rsqrtf(var + 1e-6f);
    float y0 = (v0-mean)*inv*g[t]     + bia[t];
    float y1 = (v1-mean)*inv*g[t+256] + bia[t+256];
    float y2 = (v2-mean)*inv*g[t+512] + bia[t+512];
    float lmax = fmaxf(fabsf(y0), fmaxf(fabsf(y1), fabsf(y2)));
    __syncthreads();
    rs[t] = lmax; __syncthreads();
    for (int o = 128; o; o >>= 1) {
        if (t < o) rs[t] = fmaxf(rs[t], rs[t+o]);
        __syncthreads();
    }
    if (t == 0) atomicMax(slot, __float_as_uint(rs[0]));
}

// ---------------- LayerNorm pass 2: recompute y, emit int8 k = clip(round(y/s1)) ----------------
__global__ __launch_bounds__(256) void ln_quant(
    const float* __restrict__ x, const float* __restrict__ g, const float* __restrict__ bia,
    char* __restrict__ yq, const unsigned int* __restrict__ slot)
{
    const int C = 768;
    int row = blockIdx.x, t = threadIdx.x;
    const float* xr = x + (size_t)row * C;
    float v0 = xr[t], v1 = xr[t+256], v2 = xr[t+512];
    __shared__ float rs[256], rss[256];
    rs[t] = v0+v1+v2; rss[t] = v0*v0+v1*v1+v2*v2; __syncthreads();
    for (int o = 128; o; o >>= 1) {
        if (t < o) { rs[t] += rs[t+o]; rss[t] += rss[t+o]; }
        __syncthreads();
    }
    float mean = rs[0] * (1.0f/768.0f);
    float var  = rss[0] * (1.0f/768.0f) - mean*mean;
    float inv  = rsqrtf(var + 1e-6f);
    float s1 = __uint_as_float(*slot) / QMAX + 1e-8f;
    float y0 = (v0-mean)*inv*g[t]     + bia[t];
    float y1 = (v1-mean)*inv*g[t+256] + bia[t+256];
    float y2 = (v2-mean)*inv*g[t+512] + bia[t+512];
    char* yr = yq + (size_t)row * C;
    yr[t]     = (char)(int)fminf(fmaxf(rintf(y0/s1), -QMAX), QMAX);
    yr[t+256] = (char)(int)fminf(fmaxf(rintf(y1/s1), -QMAX), QMAX);
    yr[t+512] = (char)(int)fminf(fmaxf(rintf(y2/s1), -QMAX), QMAX);
}

// ---------------- int8 MFMA GEMM: out[m,n] = sA*sW * sum_k kA[m,k]*kW[n,k] + bias[n] ----------------
// A rows < split_row come from Alo, rows >= split_row from Ahi (both natural gm*K offsets).
// Staging is a pure 16B copy. i32 accum exact; float(acc) exact (<2^24).
__global__ __launch_bounds__(256) void gemm_i8(
    const char* __restrict__ Alo, const char* __restrict__ Ahi, int split_row,
    const char* __restrict__ Wq,
    const float* __restrict__ bias, const float* __restrict__ residual,
    void* __restrict__ outp, int M, int N, int K,
    const unsigned int* __restrict__ slotA, float epsA,
    const unsigned int* __restrict__ slotW,
    int apply_gelu, int out_bf16, unsigned int* __restrict__ am_slot)
{
    __shared__ __align__(16) char As[128][144];   // 144B stride: ~2-way banks (free)
    __shared__ __align__(16) char Ws[128][144];
    __shared__ float sred[256];

    float sA  = __uint_as_float(*slotA) / QMAX + epsA;
    float sW  = __uint_as_float(*slotW) / QMAX + 1e-8f;

    const int t    = threadIdx.x;
    const int lane = t & 63;
    const int w    = t >> 6;
    const int wr   = w >> 1;
    const int wc   = w & 1;
    const int lr   = lane & 15;
    const int lk   = lane >> 4;
    const int m0   = blockIdx.y * 128;
    const int n0   = blockIdx.x * 128;

    int32x4 acc[4][4];
    #pragma unroll
    for (int i = 0; i < 4; ++i)
        #pragma unroll
        for (int j = 0; j < 4; ++j)
            acc[i][j] = (int32x4){0,0,0,0};

    for (int kt = 0; kt < K; kt += 128) {
        __syncthreads();
        // ---- stage A tile (128 rows x 128 int8): 4 chunks of 16B per thread ----
        #pragma unroll
        for (int i = 0; i < 4; ++i) {
            int chunk = t + 256*i;           // 0..1023
            int row   = chunk >> 3;
            int c16   = (chunk & 7) * 16;
            int gm    = m0 + row;
            int32x4 vv = (int32x4){0,0,0,0};
            if (gm < M) {
                const char* base = (gm < split_row) ? Alo : Ahi;
                vv = *reinterpret_cast<const int32x4*>(base + (size_t)gm*K + kt + c16);
            }
            *reinterpret_cast<int32x4*>(&As[row][c16]) = vv;
        }
        // ---- stage W tile (128 x 128 int8), N % 128 == 0 ----
        #pragma unroll
        for (int i = 0; i < 4; ++i) {
            int chunk = t + 256*i;
            int row   = chunk >> 3;
            int c16   = (chunk & 7) * 16;
            int32x4 vv = *reinterpret_cast<const int32x4*>(
                Wq + (size_t)(n0 + row)*K + kt + c16);
            *reinterpret_cast<int32x4*>(&Ws[row][c16]) = vv;
        }
        __syncthreads();
        // ---- compute: 2 k-steps of K=64 ----
        #pragma unroll
        for (int ks = 0; ks < 2; ++ks) {
            int32x4 af[4], bf[4];
            #pragma unroll
            for (int mi = 0; mi < 4; ++mi)
                af[mi] = *reinterpret_cast<const int32x4*>(
                    &As[wr*64 + mi*16 + lr][ks*64 + lk*16]);
            #pragma unroll
            for (int ni = 0; ni < 4; ++ni)
                bf[ni] = *reinterpret_cast<const int32x4*>(
                    &Ws[wc*64 + ni*16 + lr][ks*64 + lk*16]);
            #pragma unroll
            for (int mi = 0; mi < 4; ++mi)
                #pragma unroll
                for (int ni = 0; ni < 4; ++ni)
                    acc[mi][ni] = __builtin_amdgcn_mfma_i32_16x16x64_i8(
                        af[mi], bf[ni], acc[mi][ni], 0, 0, 0);
        }
    }

    // ---- epilogue: C/D map col=lane&15, row=(lane>>4)*4+reg ----
    float scale = sA * sW;
    float lmax = 0.f;
    #pragma unroll
    for (int mi = 0; mi < 4; ++mi) {
        #pragma unroll
        for (int j = 0; j < 4; ++j) {
            int m = m0 + wr*64 + mi*16 + lk*4 + j;
            if (m >= M) continue;
            #pragma unroll
            for (int ni = 0; ni < 4; ++ni) {
                int n = n0 + wc*64 + ni*16 + lr;
                float v = scale * (float)acc[mi][ni][j] + bias[n];
                if (residual) v += residual[(size_t)m*N + n];
                if (apply_gelu) v = 0.5f * v * (1.0f + erff(v * 0.70710678118654752f));
                if (out_bf16) {
                    unsigned short ub = f2bf(v);
                    ((unsigned short*)outp)[(size_t)m*N + n] = ub;
                    lmax = fmaxf(lmax, fabsf(bf2f(ub)));
                } else {
                    ((float*)outp)[(size_t)m*N + n] = v;
                    lmax = fmaxf(lmax, fabsf(v));
                }
            }
        }
    }
    if (am_slot) {
        sred[t] = lmax; __syncthreads();
        for (int o = 128; o; o >>= 1) {
            if (t < o) sred[t] = fmaxf(sred[t], sred[t+o]);
            __syncthreads();
        }
        if (t == 0) atomicMax(am_slot, __float_as_uint(sred[0]));
    }
}

// ---------------- MFMA flash attention (unchanged from R5) ----------------
__global__ __launch_bounds__(256) void attn_mfma(
    const unsigned short* __restrict__ qkv, unsigned short* __restrict__ xa,
    unsigned int* __restrict__ am_slot)
{
    const int Nn = 577;
    const int bh = blockIdx.y;
    const int h  = bh % 12;
    const int b  = bh / 12;
    const int q0 = blockIdx.x * 64;
    const int t  = threadIdx.x;
    const int w    = t >> 6;
    const int lane = t & 63;
    const int lr   = lane & 15;
    const int lk   = lane >> 4;

    __shared__ __align__(16) unsigned short Ks[64][72];
    __shared__ __align__(16) unsigned short Vt[64][72];
    __shared__ __align__(16) unsigned short Pw[4][16][72];
    __shared__ float sred[256];

    const size_t rowstride = 2304;
    const size_t basebh = ((size_t)b * Nn) * rowstride + (size_t)h * 64;

    bf16x8 qf[2];
    {
        int row = q0 + w*16 + lr;
        if (row < Nn) {
            const unsigned short* qrow = qkv + (size_t)row * rowstride + basebh;
            qf[0] = *reinterpret_cast<const bf16x8*>(qrow + lk*8);
            qf[1] = *reinterpret_cast<const bf16x8*>(qrow + 32 + lk*8);
        } else {
            #pragma unroll
            for (int j = 0; j < 8; ++j) { qf[0][j] = 0; qf[1][j] = 0; }
        }
    }

    float m_run[4], l_run[4];
    f32x4 acc_o[4];
    #pragma unroll
    for (int j = 0; j < 4; ++j) { m_run[j] = -INFINITY; l_run[j] = 0.f; }
    #pragma unroll
    for (int df = 0; df < 4; ++df) acc_o[df] = (f32x4){0.f,0.f,0.f,0.f};

    for (int kt = 0; kt < 10; ++kt) {
        __syncthreads();
        #pragma unroll
        for (int pass = 0; pass < 2; ++pass) {
            int r   = (t >> 3) + pass*32;
            int e8  = (t & 7) * 8;
            int key = kt*64 + r;
            ushortx8 ku, vu;
            if (key < Nn) {
                const unsigned short* krow = qkv + (size_t)key * rowstride + basebh;
                ku = *reinterpret_cast<const ushortx8*>(krow + 768  + e8);
                vu = *reinterpret_cast<const ushortx8*>(krow + 1536 + e8);
            } else {
                #pragma unroll
                for (int j = 0; j < 8; ++j) { ku[j] = 0; vu[j] = 0; }
            }
            *reinterpret_cast<ushortx8*>(&Ks[r][e8]) = ku;
            #pragma unroll
            for (int j = 0; j < 8; ++j) Vt[e8 + j][r] = vu[j];
        }
        __syncthreads();

        f32x4 s[4];
        #pragma unroll
        for (int nf = 0; nf < 4; ++nf) s[nf] = (f32x4){0.f,0.f,0.f,0.f};
        #pragma unroll
        for (int kk = 0; kk < 2; ++kk) {
            #pragma unroll
            for (int nf = 0; nf < 4; ++nf) {
                bf16x8 kfrag = *reinterpret_cast<const bf16x8*>(
                    &Ks[nf*16 + lr][kk*32 + lk*8]);
                s[nf] = __builtin_amdgcn_mfma_f32_16x16x32_bf16(
                    qf[kk], kfrag, s[nf], 0, 0, 0);
            }
        }
        #pragma unroll
        for (int nf = 0; nf < 4; ++nf) {
            int key = kt*64 + nf*16 + lr;
            bool valid = key < Nn;
            #pragma unroll
            for (int j = 0; j < 4; ++j)
                s[nf][j] = valid ? s[nf][j] * 0.125f : -INFINITY;
        }

        float tmax[4];
        #pragma unroll
        for (int j = 0; j < 4; ++j)
            tmax[j] = fmaxf(fmaxf(s[0][j], s[1][j]), fmaxf(s[2][j], s[3][j]));
        #pragma unroll
        for (int off = 1; off <= 8; off <<= 1)
            #pragma unroll
            for (int j = 0; j < 4; ++j)
                tmax[j] = fmaxf(tmax[j], __shfl_xor(tmax[j], off));
        float fac[4];
        #pragma unroll
        for (int j = 0; j < 4; ++j) {
            float nm = fmaxf(m_run[j], tmax[j]);
            fac[j] = __expf(m_run[j] - nm);
            m_run[j] = nm;
        }
        float psum[4] = {0.f,0.f,0.f,0.f};
        #pragma unroll
        for (int nf = 0; nf < 4; ++nf)
            #pragma unroll
            for (int j = 0; j < 4; ++j) {
                float p = __expf(s[nf][j] - m_run[j]);
                s[nf][j] = p;
                psum[j] += p;
            }
        #pragma unroll
        for (int off = 1; off <= 8; off <<= 1)
            #pragma unroll
            for (int j = 0; j < 4; ++j)
                psum[j] += __shfl_xor(psum[j], off);
        #pragma unroll
        for (int j = 0; j < 4; ++j)
            l_run[j] = l_run[j] * fac[j] + psum[j];
        #pragma unroll
        for (int df = 0; df < 4; ++df)
            #pragma unroll
            for (int j = 0; j < 4; ++j)
                acc_o[df][j] *= fac[j];

        #pragma unroll
        for (int nf = 0; nf < 4; ++nf)
            #pragma unroll
            for (int j = 0; j < 4; ++j)
                Pw[w][lk*4 + j][nf*16 + lr] = f2bf(s[nf][j]);
        __syncthreads();

        #pragma unroll
        for (int kk = 0; kk < 2; ++kk) {
            bf16x8 pf = *reinterpret_cast<const bf16x8*>(
                &Pw[w][lr][kk*32 + lk*8]);
            #pragma unroll
            for (int df = 0; df < 4; ++df) {
                bf16x8 vf = *reinterpret_cast<const bf16x8*>(
                    &Vt[df*16 + lr][kk*32 + lk*8]);
                acc_o[df] = __builtin_amdgcn_mfma_f32_16x16x32_bf16(
                    pf, vf, acc_o[df], 0, 0, 0);
            }
        }
    }

    float lmax = 0.f;
    #pragma unroll
    for (int j = 0; j < 4; ++j) {
        int m = q0 + w*16 + lk*4 + j;
        if (m < Nn) {
            float rl = 1.0f / l_run[j];
            #pragma unroll
            for (int df = 0; df < 4; ++df) {
                int d = df*16 + lr;
                float o = acc_o[df][j] * rl;
                unsigned short ob = f2bf(o);
                xa[((size_t)(b*Nn + m))*768 + h*64 + d] = ob;
                lmax = fmaxf(lmax, fabsf(bf2f(ob)));
            }
        }
    }
    sred[t] = lmax; __syncthreads();
    for (int o = 128; o; o >>= 1) {
        if (t < o) sred[t] = fmaxf(sred[t], sred[t+o]);
        __syncthreads();
    }
    if (t == 0) atomicMax(am_slot, __float_as_uint(sred[0]));
}

extern "C" void kernel_launch(void* const* d_in, const int* in_sizes, int n_in,
                              void* d_out, int out_size, void* d_ws, size_t ws_size,
                              hipStream_t stream)
{
    const float* x      = (const float*)d_in[0];
    const float* ln1_g  = (const float*)d_in[1];
    const float* ln1_b  = (const float*)d_in[2];
    const float* qkv_w  = (const float*)d_in[3];
    const float* qkv_b  = (const float*)d_in[4];
    const float* proj_w = (const float*)d_in[5];
    const float* proj_b = (const float*)d_in[6];
    const float* ln2_g  = (const float*)d_in[7];
    const float* ln2_b  = (const float*)d_in[8];
    const float* fc1_w  = (const float*)d_in[9];
    const float* fc1_b  = (const float*)d_in[10];
    const float* fc2_w  = (const float*)d_in[11];
    const float* fc2_b  = (const float*)d_in[12];
    float* out = (float*)d_out;

    const int B = 32, Nn = 577, C = 768, H3 = 3072;
    const int M = B * Nn;                    // 18464
    const size_t nA = (size_t)M * C;         // 14,180,352
    const size_t nQ = (size_t)M * 3 * C;
    const size_t nH = (size_t)M * H3;        // 56,721,408

    const size_t NEEDED = 256 + 2359296 + nA + 2*nH;
    if (ws_size < NEEDED) return;

    char* wsb = (char*)d_ws;
    unsigned int* am = (unsigned int*)wsb;
    char* WQ  = wsb + 256;
    char* XNQ = WQ + 2359296;                 // 14.18 MB int8 slot (ln out / xaq / hq-side)
    char* BIG = XNQ + nA;
    unsigned short* QKV = (unsigned short*)BIG;
    unsigned short* XA  = (unsigned short*)(BIG + 2*nQ);
    unsigned short* Hbf = (unsigned short*)BIG;
    char* HQ = BIG;                           // in-place int8 h (rows >= SPLIT)

    const int SPLIT = 4608;                   // h rows [0,SPLIT) live in XNQ slot
    const size_t rowsB = 9216 - 4608, rowsC = 18432 - 9216, rowsD = 18464 - 18432;

    dim3 blk(256);
    int mt128 = (M + 127) / 128;

    init_slots<<<dim3(1), dim3(16), 0, stream>>>(am);

    // ---- attention branch ----
    ln_absmax<<<dim3(M), blk, 0, stream>>>(x, ln1_g, ln1_b, am + 0);
    ln_quant <<<dim3(M), blk, 0, stream>>>(x, ln1_g, ln1_b, XNQ, am + 0);

    absmax_f32<<<dim3(1024), blk, 0, stream>>>(qkv_w, (size_t)3*C*C, am + 6);
    quant_w  <<<dim3(1024), blk, 0, stream>>>(qkv_w, WQ, (size_t)3*C*C, am + 6);
    gemm_i8<<<dim3(3*C/128, mt128), blk, 0, stream>>>(
        XNQ, XNQ, 0, WQ, qkv_b, nullptr, QKV, M, 3*C, C,
        am + 0, 2e-8f, am + 6, 0, 1, nullptr);

    attn_mfma<<<dim3(10, 384), blk, 0, stream>>>(QKV, XA, am + 2);

    // xa -> int8 (XNQ slot is dead here; proj consumes it before ln2 rewrites it)
    quant_bf2i8<<<dim3(2048), blk, 0, stream>>>(XA, XNQ, nA/8, am + 2);

    absmax_f32<<<dim3(1024), blk, 0, stream>>>(proj_w, (size_t)C*C, am + 7);
    quant_w  <<<dim3(1024), blk, 0, stream>>>(proj_w, WQ, (size_t)C*C, am + 7);
    gemm_i8<<<dim3(C/128, mt128), blk, 0, stream>>>(
        XNQ, XNQ, 0, WQ, proj_b, x, out, M, C, C,
        am + 2, 1e-8f, am + 7, 0, 0, nullptr);          // out = x + proj

    // ---- mlp branch ----
    ln_absmax<<<dim3(M), blk, 0, stream>>>(out, ln2_g, ln2_b, am + 4);
    ln_quant <<<dim3(M), blk, 0, stream>>>(out, ln2_g, ln2_b, XNQ, am + 4);

    absmax_f32<<<dim3(1024), blk, 0, stream>>>(fc1_w, (size_t)H3*C, am + 8);
    quant_w  <<<dim3(1024), blk, 0, stream>>>(fc1_w, WQ, (size_t)H3*C, am + 8);
    gemm_i8<<<dim3(H3/128, mt128), blk, 0, stream>>>(
        XNQ, XNQ, 0, WQ, fc1_b, nullptr, Hbf, M, H3, C,
        am + 4, 2e-8f, am + 8, 1, 1, am + 3);           // gelu, bf16 h, absmax(h)

    // h -> int8: side chunk to XNQ slot, then in-place compaction (ordered,
    // write/read byte ranges disjoint per launch; see analysis)
    quant_bf2i8<<<dim3(2048), blk, 0, stream>>>(
        Hbf, XNQ, (size_t)SPLIT*H3/8, am + 3);
    quant_bf2i8<<<dim3(2048), blk, 0, stream>>>(
        Hbf + (size_t)4608*H3, HQ + (size_t)4608*H3, rowsB*H3/8, am + 3);
    quant_bf2i8<<<dim3(2048), blk, 0, stream>>>(
        Hbf + (size_t)9216*H3, HQ + (size_t)9216*H3, rowsC*H3/8, am + 3);
    quant_bf2i8<<<dim3(48),  blk, 0, stream>>>(
        Hbf + (size_t)18432*H3, HQ + (size_t)18432*H3, rowsD*H3/8, am + 3);

    absmax_f32<<<dim3(1024), blk, 0, stream>>>(fc2_w, (size_t)C*H3, am + 9);
    quant_w  <<<dim3(1024), blk, 0, stream>>>(fc2_w, WQ, (size_t)C*H3, am + 9);
    gemm_i8<<<dim3(C/128, mt128), blk, 0, stream>>>(
        XNQ, HQ, SPLIT, WQ, fc2_b, out, out, M, C, H3,
        am + 3, 1e-8f, am + 9, 0, 0, nullptr);          // out += fc2
}

// Round 8
// 908.693 us; speedup vs baseline: 9.4158x; 1.4283x over previous
//
#include <hip/hip_runtime.h>
#include <hip/hip_bf16.h>
#include <math.h>

#define QMAX 127.0f

// ---- absmax slots (uint-as-float bits) ----
// 0: ln1 y   2: xa(bf16)   3: h(gelu,bf16)   4: ln2 y
// 6: qkv_w   7: proj_w     8: fc1_w          9: fc2_w

typedef unsigned short ushortx8 __attribute__((ext_vector_type(8)));
typedef short bf16x8 __attribute__((ext_vector_type(8)));
typedef float f32x4 __attribute__((ext_vector_type(4)));
typedef int int32x4 __attribute__((ext_vector_type(4)));

__device__ inline float bf2f(unsigned short u) {
    return __uint_as_float(((unsigned int)u) << 16);
}
__device__ inline unsigned short f2bf(float f) {
    __hip_bfloat16 h = __float2bfloat16(f);   // round-to-nearest-even
    return *reinterpret_cast<unsigned short*>(&h);
}

__global__ void init_slots(unsigned int* am) {
    if (threadIdx.x < 16) am[threadIdx.x] = 0u;
}

// ---------------- absmax over fp32 array ----------------
__global__ __launch_bounds__(256) void absmax_f32(
    const float* __restrict__ p, size_t n, unsigned int* __restrict__ slot)
{
    float lmax = 0.f;
    for (size_t i = (size_t)blockIdx.x*256 + threadIdx.x; i < n; i += (size_t)gridDim.x*256)
        lmax = fmaxf(lmax, fabsf(p[i]));
    __shared__ float rs[256];
    int t = threadIdx.x;
    rs[t] = lmax; __syncthreads();
    for (int o = 128; o; o >>= 1) {
        if (t < o) rs[t] = fmaxf(rs[t], rs[t+o]);
        __syncthreads();
    }
    if (t == 0) atomicMax(slot, __float_as_uint(rs[0]));
}

// ---------------- weight quantize: fp32 -> int8 ----------------
__global__ __launch_bounds__(256) void quant_w(
    const float* __restrict__ w, char* __restrict__ q, size_t n,
    const unsigned int* __restrict__ slot)
{
    float s = __uint_as_float(*slot) / QMAX + 1e-8f;
    for (size_t i = (size_t)blockIdx.x*256 + threadIdx.x; i < n; i += (size_t)gridDim.x*256) {
        float k = fminf(fmaxf(rintf(w[i] / s), -QMAX), QMAX);
        q[i] = (char)(int)k;
    }
}

// ---------------- activation quantize: bf16 -> int8 (8 elems/thread/iter) ----------------
__global__ __launch_bounds__(256) void quant_bf2i8(
    const unsigned short* __restrict__ src, char* __restrict__ dst, size_t n8,
    const unsigned int* __restrict__ slot)
{
    float s  = __uint_as_float(*slot) / QMAX + 1e-8f;
    float rs = 1.0f / s;
    for (size_t i = (size_t)blockIdx.x*256 + threadIdx.x; i < n8; i += (size_t)gridDim.x*256) {
        ushortx8 u = *reinterpret_cast<const ushortx8*>(src + i*8);
        int lo = 0, hi = 0;
        #pragma unroll
        for (int j = 0; j < 4; ++j) {
            int k = (int)fminf(fmaxf(rintf(bf2f(u[j]) * rs), -QMAX), QMAX);
            lo |= (k & 0xff) << (8*j);
        }
        #pragma unroll
        for (int j = 0; j < 4; ++j) {
            int k = (int)fminf(fmaxf(rintf(bf2f(u[4+j]) * rs), -QMAX), QMAX);
            hi |= (k & 0xff) << (8*j);
        }
        reinterpret_cast<int2*>(dst)[i] = make_int2(lo, hi);
    }
}

// ---------------- LayerNorm pass 1: absmax(y), wave-per-row ----------------
// 64 lanes x 12 elems (3 float4). Pure shfl reductions, one atomic per block.
__global__ __launch_bounds__(256) void ln_absmax(
    const float* __restrict__ x, const float* __restrict__ g, const float* __restrict__ bia,
    int nrows, unsigned int* __restrict__ slot)
{
    const int lane = threadIdx.x & 63;
    const int wv   = threadIdx.x >> 6;
    int wid = blockIdx.x*4 + wv;
    int nw  = gridDim.x*4;
    const float4* g4 = reinterpret_cast<const float4*>(g);
    const float4* b4 = reinterpret_cast<const float4*>(bia);
    float4 ga = g4[lane], gb = g4[lane+64], gc = g4[lane+128];
    float4 ba = b4[lane], bb = b4[lane+64], bc = b4[lane+128];
    float wmax = 0.f;
    for (int row = wid; row < nrows; row += nw) {
        const float4* xr = reinterpret_cast<const float4*>(x + (size_t)row*768);
        float4 xa = xr[lane], xb = xr[lane+64], xc = xr[lane+128];
        float s  = xa.x+xa.y+xa.z+xa.w + xb.x+xb.y+xb.z+xb.w + xc.x+xc.y+xc.z+xc.w;
        float ss = xa.x*xa.x+xa.y*xa.y+xa.z*xa.z+xa.w*xa.w
                 + xb.x*xb.x+xb.y*xb.y+xb.z*xb.z+xb.w*xb.w
                 + xc.x*xc.x+xc.y*xc.y+xc.z*xc.z+xc.w*xc.w;
        #pragma unroll
        for (int off = 32; off; off >>= 1) {
            s  += __shfl_xor(s,  off);
            ss += __shfl_xor(ss, off);
        }
        float mean = s * (1.0f/768.0f);
        float inv  = rsqrtf(ss * (1.0f/768.0f) - mean*mean + 1e-6f);
        float m = 0.f;
        m = fmaxf(m, fabsf((xa.x-mean)*inv*ga.x + ba.x));
        m = fmaxf(m, fabsf((xa.y-mean)*inv*ga.y + ba.y));
        m = fmaxf(m, fabsf((xa.z-mean)*inv*ga.z + ba.z));
        m = fmaxf(m, fabsf((xa.w-mean)*inv*ga.w + ba.w));
        m = fmaxf(m, fabsf((xb.x-mean)*inv*gb.x + bb.x));
        m = fmaxf(m, fabsf((xb.y-mean)*inv*gb.y + bb.y));
        m = fmaxf(m, fabsf((xb.z-mean)*inv*gb.z + bb.z));
        m = fmaxf(m, fabsf((xb.w-mean)*inv*gb.w + bb.w));
        m = fmaxf(m, fabsf((xc.x-mean)*inv*gc.x + bc.x));
        m = fmaxf(m, fabsf((xc.y-mean)*inv*gc.y + bc.y));
        m = fmaxf(m, fabsf((xc.z-mean)*inv*gc.z + bc.z));
        m = fmaxf(m, fabsf((xc.w-mean)*inv*gc.w + bc.w));
        wmax = fmaxf(wmax, m);
    }
    #pragma unroll
    for (int off = 32; off; off >>= 1)
        wmax = fmaxf(wmax, __shfl_xor(wmax, off));
    __shared__ float red[4];
    if (lane == 0) red[wv] = wmax;
    __syncthreads();
    if (threadIdx.x == 0) {
        float m = fmaxf(fmaxf(red[0], red[1]), fmaxf(red[2], red[3]));
        atomicMax(slot, __float_as_uint(m));
    }
}

// ---------------- LayerNorm pass 2: wave-per-row, emit packed int8 ----------------
__global__ __launch_bounds__(256) void ln_quant(
    const float* __restrict__ x, const float* __restrict__ g, const float* __restrict__ bia,
    int nrows, char* __restrict__ yq, const unsigned int* __restrict__ slot)
{
    const int lane = threadIdx.x & 63;
    const int wv   = threadIdx.x >> 6;
    int wid = blockIdx.x*4 + wv;
    int nw  = gridDim.x*4;
    const float4* g4 = reinterpret_cast<const float4*>(g);
    const float4* b4 = reinterpret_cast<const float4*>(bia);
    float4 ga = g4[lane], gb = g4[lane+64], gc = g4[lane+128];
    float4 ba = b4[lane], bb = b4[lane+64], bc = b4[lane+128];
    float s1 = __uint_as_float(*slot) / QMAX + 1e-8f;
    float r1 = 1.0f / s1;
    for (int row = wid; row < nrows; row += nw) {
        const float4* xr = reinterpret_cast<const float4*>(x + (size_t)row*768);
        float4 xa = xr[lane], xb = xr[lane+64], xc = xr[lane+128];
        float s  = xa.x+xa.y+xa.z+xa.w + xb.x+xb.y+xb.z+xb.w + xc.x+xc.y+xc.z+xc.w;
        float ss = xa.x*xa.x+xa.y*xa.y+xa.z*xa.z+xa.w*xa.w
                 + xb.x*xb.x+xb.y*xb.y+xb.z*xb.z+xb.w*xb.w
                 + xc.x*xc.x+xc.y*xc.y+xc.z*xc.z+xc.w*xc.w;
        #pragma unroll
        for (int off = 32; off; off >>= 1) {
            s  += __shfl_xor(s,  off);
            ss += __shfl_xor(ss, off);
        }
        float mean = s * (1.0f/768.0f);
        float inv  = rsqrtf(ss * (1.0f/768.0f) - mean*mean + 1e-6f);
        int* yr = reinterpret_cast<int*>(yq + (size_t)row*768);
        float y0, y1, y2, y3;
        int p;
        y0 = (xa.x-mean)*inv*ga.x + ba.x; y1 = (xa.y-mean)*inv*ga.y + ba.y;
        y2 = (xa.z-mean)*inv*ga.z + ba.z; y3 = (xa.w-mean)*inv*ga.w + ba.w;
        p  = ((int)fminf(fmaxf(rintf(y0*r1), -QMAX), QMAX) & 0xff)
           | (((int)fminf(fmaxf(rintf(y1*r1), -QMAX), QMAX) & 0xff) << 8)
           | (((int)fminf(fmaxf(rintf(y2*r1), -QMAX), QMAX) & 0xff) << 16)
           | (((int)fminf(fmaxf(rintf(y3*r1), -QMAX), QMAX) & 0xff) << 24);
        yr[lane] = p;
        y0 = (xb.x-mean)*inv*gb.x + bb.x; y1 = (xb.y-mean)*inv*gb.y + bb.y;
        y2 = (xb.z-mean)*inv*gb.z + bb.z; y3 = (xb.w-mean)*inv*gb.w + bb.w;
        p  = ((int)fminf(fmaxf(rintf(y0*r1), -QMAX), QMAX) & 0xff)
           | (((int)fminf(fmaxf(rintf(y1*r1), -QMAX), QMAX) & 0xff) << 8)
           | (((int)fminf(fmaxf(rintf(y2*r1), -QMAX), QMAX) & 0xff) << 16)
           | (((int)fminf(fmaxf(rintf(y3*r1), -QMAX), QMAX) & 0xff) << 24);
        yr[lane+64] = p;
        y0 = (xc.x-mean)*inv*gc.x + bc.x; y1 = (xc.y-mean)*inv*gc.y + bc.y;
        y2 = (xc.z-mean)*inv*gc.z + bc.z; y3 = (xc.w-mean)*inv*gc.w + bc.w;
        p  = ((int)fminf(fmaxf(rintf(y0*r1), -QMAX), QMAX) & 0xff)
           | (((int)fminf(fmaxf(rintf(y1*r1), -QMAX), QMAX) & 0xff) << 8)
           | (((int)fminf(fmaxf(rintf(y2*r1), -QMAX), QMAX) & 0xff) << 16)
           | (((int)fminf(fmaxf(rintf(y3*r1), -QMAX), QMAX) & 0xff) << 24);
        yr[lane+128] = p;
    }
}

// ---------------- int8 MFMA GEMM (unchanged from R7) ----------------
__global__ __launch_bounds__(256) void gemm_i8(
    const char* __restrict__ Alo, const char* __restrict__ Ahi, int split_row,
    const char* __restrict__ Wq,
    const float* __restrict__ bias, const float* __restrict__ residual,
    void* __restrict__ outp, int M, int N, int K,
    const unsigned int* __restrict__ slotA, float epsA,
    const unsigned int* __restrict__ slotW,
    int apply_gelu, int out_bf16, unsigned int* __restrict__ am_slot)
{
    __shared__ __align__(16) char As[128][144];
    __shared__ __align__(16) char Ws[128][144];
    __shared__ float sred[256];

    float sA  = __uint_as_float(*slotA) / QMAX + epsA;
    float sW  = __uint_as_float(*slotW) / QMAX + 1e-8f;

    const int t    = threadIdx.x;
    const int lane = t & 63;
    const int w    = t >> 6;
    const int wr   = w >> 1;
    const int wc   = w & 1;
    const int lr   = lane & 15;
    const int lk   = lane >> 4;
    const int m0   = blockIdx.y * 128;
    const int n0   = blockIdx.x * 128;

    int32x4 acc[4][4];
    #pragma unroll
    for (int i = 0; i < 4; ++i)
        #pragma unroll
        for (int j = 0; j < 4; ++j)
            acc[i][j] = (int32x4){0,0,0,0};

    for (int kt = 0; kt < K; kt += 128) {
        __syncthreads();
        #pragma unroll
        for (int i = 0; i < 4; ++i) {
            int chunk = t + 256*i;
            int row   = chunk >> 3;
            int c16   = (chunk & 7) * 16;
            int gm    = m0 + row;
            int32x4 vv = (int32x4){0,0,0,0};
            if (gm < M) {
                const char* base = (gm < split_row) ? Alo : Ahi;
                vv = *reinterpret_cast<const int32x4*>(base + (size_t)gm*K + kt + c16);
            }
            *reinterpret_cast<int32x4*>(&As[row][c16]) = vv;
        }
        #pragma unroll
        for (int i = 0; i < 4; ++i) {
            int chunk = t + 256*i;
            int row   = chunk >> 3;
            int c16   = (chunk & 7) * 16;
            int32x4 vv = *reinterpret_cast<const int32x4*>(
                Wq + (size_t)(n0 + row)*K + kt + c16);
            *reinterpret_cast<int32x4*>(&Ws[row][c16]) = vv;
        }
        __syncthreads();
        #pragma unroll
        for (int ks = 0; ks < 2; ++ks) {
            int32x4 af[4], bf[4];
            #pragma unroll
            for (int mi = 0; mi < 4; ++mi)
                af[mi] = *reinterpret_cast<const int32x4*>(
                    &As[wr*64 + mi*16 + lr][ks*64 + lk*16]);
            #pragma unroll
            for (int ni = 0; ni < 4; ++ni)
                bf[ni] = *reinterpret_cast<const int32x4*>(
                    &Ws[wc*64 + ni*16 + lr][ks*64 + lk*16]);
            #pragma unroll
            for (int mi = 0; mi < 4; ++mi)
                #pragma unroll
                for (int ni = 0; ni < 4; ++ni)
                    acc[mi][ni] = __builtin_amdgcn_mfma_i32_16x16x64_i8(
                        af[mi], bf[ni], acc[mi][ni], 0, 0, 0);
        }
    }

    float scale = sA * sW;
    float lmax = 0.f;
    #pragma unroll
    for (int mi = 0; mi < 4; ++mi) {
        #pragma unroll
        for (int j = 0; j < 4; ++j) {
            int m = m0 + wr*64 + mi*16 + lk*4 + j;
            if (m >= M) continue;
            #pragma unroll
            for (int ni = 0; ni < 4; ++ni) {
                int n = n0 + wc*64 + ni*16 + lr;
                float v = scale * (float)acc[mi][ni][j] + bias[n];
                if (residual) v += residual[(size_t)m*N + n];
                if (apply_gelu) v = 0.5f * v * (1.0f + erff(v * 0.70710678118654752f));
                if (out_bf16) {
                    unsigned short ub = f2bf(v);
                    ((unsigned short*)outp)[(size_t)m*N + n] = ub;
                    lmax = fmaxf(lmax, fabsf(bf2f(ub)));
                } else {
                    ((float*)outp)[(size_t)m*N + n] = v;
                    lmax = fmaxf(lmax, fabsf(v));
                }
            }
        }
    }
    if (am_slot) {
        sred[t] = lmax; __syncthreads();
        for (int o = 128; o; o >>= 1) {
            if (t < o) sred[t] = fmaxf(sred[t], sred[t+o]);
            __syncthreads();
        }
        if (t == 0) atomicMax(am_slot, __float_as_uint(sred[0]));
    }
}

// ---------------- MFMA flash attention (unchanged from R5) ----------------
__global__ __launch_bounds__(256) void attn_mfma(
    const unsigned short* __restrict__ qkv, unsigned short* __restrict__ xa,
    unsigned int* __restrict__ am_slot)
{
    const int Nn = 577;
    const int bh = blockIdx.y;
    const int h  = bh % 12;
    const int b  = bh / 12;
    const int q0 = blockIdx.x * 64;
    const int t  = threadIdx.x;
    const int w    = t >> 6;
    const int lane = t & 63;
    const int lr   = lane & 15;
    const int lk   = lane >> 4;

    __shared__ __align__(16) unsigned short Ks[64][72];
    __shared__ __align__(16) unsigned short Vt[64][72];
    __shared__ __align__(16) unsigned short Pw[4][16][72];
    __shared__ float sred[256];

    const size_t rowstride = 2304;
    const size_t basebh = ((size_t)b * Nn) * rowstride + (size_t)h * 64;

    bf16x8 qf[2];
    {
        int row = q0 + w*16 + lr;
        if (row < Nn) {
            const unsigned short* qrow = qkv + (size_t)row * rowstride + basebh;
            qf[0] = *reinterpret_cast<const bf16x8*>(qrow + lk*8);
            qf[1] = *reinterpret_cast<const bf16x8*>(qrow + 32 + lk*8);
        } else {
            #pragma unroll
            for (int j = 0; j < 8; ++j) { qf[0][j] = 0; qf[1][j] = 0; }
        }
    }

    float m_run[4], l_run[4];
    f32x4 acc_o[4];
    #pragma unroll
    for (int j = 0; j < 4; ++j) { m_run[j] = -INFINITY; l_run[j] = 0.f; }
    #pragma unroll
    for (int df = 0; df < 4; ++df) acc_o[df] = (f32x4){0.f,0.f,0.f,0.f};

    for (int kt = 0; kt < 10; ++kt) {
        __syncthreads();
        #pragma unroll
        for (int pass = 0; pass < 2; ++pass) {
            int r   = (t >> 3) + pass*32;
            int e8  = (t & 7) * 8;
            int key = kt*64 + r;
            ushortx8 ku, vu;
            if (key < Nn) {
                const unsigned short* krow = qkv + (size_t)key * rowstride + basebh;
                ku = *reinterpret_cast<const ushortx8*>(krow + 768  + e8);
                vu = *reinterpret_cast<const ushortx8*>(krow + 1536 + e8);
            } else {
                #pragma unroll
                for (int j = 0; j < 8; ++j) { ku[j] = 0; vu[j] = 0; }
            }
            *reinterpret_cast<ushortx8*>(&Ks[r][e8]) = ku;
            #pragma unroll
            for (int j = 0; j < 8; ++j) Vt[e8 + j][r] = vu[j];
        }
        __syncthreads();

        f32x4 s[4];
        #pragma unroll
        for (int nf = 0; nf < 4; ++nf) s[nf] = (f32x4){0.f,0.f,0.f,0.f};
        #pragma unroll
        for (int kk = 0; kk < 2; ++kk) {
            #pragma unroll
            for (int nf = 0; nf < 4; ++nf) {
                bf16x8 kfrag = *reinterpret_cast<const bf16x8*>(
                    &Ks[nf*16 + lr][kk*32 + lk*8]);
                s[nf] = __builtin_amdgcn_mfma_f32_16x16x32_bf16(
                    qf[kk], kfrag, s[nf], 0, 0, 0);
            }
        }
        #pragma unroll
        for (int nf = 0; nf < 4; ++nf) {
            int key = kt*64 + nf*16 + lr;
            bool valid = key < Nn;
            #pragma unroll
            for (int j = 0; j < 4; ++j)
                s[nf][j] = valid ? s[nf][j] * 0.125f : -INFINITY;
        }

        float tmax[4];
        #pragma unroll
        for (int j = 0; j < 4; ++j)
            tmax[j] = fmaxf(fmaxf(s[0][j], s[1][j]), fmaxf(s[2][j], s[3][j]));
        #pragma unroll
        for (int off = 1; off <= 8; off <<= 1)
            #pragma unroll
            for (int j = 0; j < 4; ++j)
                tmax[j] = fmaxf(tmax[j], __shfl_xor(tmax[j], off));
        float fac[4];
        #pragma unroll
        for (int j = 0; j < 4; ++j) {
            float nm = fmaxf(m_run[j], tmax[j]);
            fac[j] = __expf(m_run[j] - nm);
            m_run[j] = nm;
        }
        float psum[4] = {0.f,0.f,0.f,0.f};
        #pragma unroll
        for (int nf = 0; nf < 4; ++nf)
            #pragma unroll
            for (int j = 0; j < 4; ++j) {
                float p = __expf(s[nf][j] - m_run[j]);
                s[nf][j] = p;
                psum[j] += p;
            }
        #pragma unroll
        for (int off = 1; off <= 8; off <<= 1)
            #pragma unroll
            for (int j = 0; j < 4; ++j)
                psum[j] += __shfl_xor(psum[j], off);
        #pragma unroll
        for (int j = 0; j < 4; ++j)
            l_run[j] = l_run[j] * fac[j] + psum[j];
        #pragma unroll
        for (int df = 0; df < 4; ++df)
            #pragma unroll
            for (int j = 0; j < 4; ++j)
                acc_o[df][j] *= fac[j];

        #pragma unroll
        for (int nf = 0; nf < 4; ++nf)
            #pragma unroll
            for (int j = 0; j < 4; ++j)
                Pw[w][lk*4 + j][nf*16 + lr] = f2bf(s[nf][j]);
        __syncthreads();

        #pragma unroll
        for (int kk = 0; kk < 2; ++kk) {
            bf16x8 pf = *reinterpret_cast<const bf16x8*>(
                &Pw[w][lr][kk*32 + lk*8]);
            #pragma unroll
            for (int df = 0; df < 4; ++df) {
                bf16x8 vf = *reinterpret_cast<const bf16x8*>(
                    &Vt[df*16 + lr][kk*32 + lk*8]);
                acc_o[df] = __builtin_amdgcn_mfma_f32_16x16x32_bf16(
                    pf, vf, acc_o[df], 0, 0, 0);
            }
        }
    }

    float lmax = 0.f;
    #pragma unroll
    for (int j = 0; j < 4; ++j) {
        int m = q0 + w*16 + lk*4 + j;
        if (m < Nn) {
            float rl = 1.0f / l_run[j];
            #pragma unroll
            for (int df = 0; df < 4; ++df) {
                int d = df*16 + lr;
                float o = acc_o[df][j] * rl;
                unsigned short ob = f2bf(o);
                xa[((size_t)(b*Nn + m))*768 + h*64 + d] = ob;
                lmax = fmaxf(lmax, fabsf(bf2f(ob)));
            }
        }
    }
    sred[t] = lmax; __syncthreads();
    for (int o = 128; o; o >>= 1) {
        if (t < o) sred[t] = fmaxf(sred[t], sred[t+o]);
        __syncthreads();
    }
    if (t == 0) atomicMax(am_slot, __float_as_uint(sred[0]));
}

extern "C" void kernel_launch(void* const* d_in, const int* in_sizes, int n_in,
                              void* d_out, int out_size, void* d_ws, size_t ws_size,
                              hipStream_t stream)
{
    const float* x      = (const float*)d_in[0];
    const float* ln1_g  = (const float*)d_in[1];
    const float* ln1_b  = (const float*)d_in[2];
    const float* qkv_w  = (const float*)d_in[3];
    const float* qkv_b  = (const float*)d_in[4];
    const float* proj_w = (const float*)d_in[5];
    const float* proj_b = (const float*)d_in[6];
    const float* ln2_g  = (const float*)d_in[7];
    const float* ln2_b  = (const float*)d_in[8];
    const float* fc1_w  = (const float*)d_in[9];
    const float* fc1_b  = (const float*)d_in[10];
    const float* fc2_w  = (const float*)d_in[11];
    const float* fc2_b  = (const float*)d_in[12];
    float* out = (float*)d_out;

    const int B = 32, Nn = 577, C = 768, H3 = 3072;
    const int M = B * Nn;                    // 18464
    const size_t nA = (size_t)M * C;         // 14,180,352
    const size_t nQ = (size_t)M * 3 * C;
    const size_t nH = (size_t)M * H3;        // 56,721,408

    const size_t NEEDED = 256 + 2359296 + nA + 2*nH;
    if (ws_size < NEEDED) return;

    char* wsb = (char*)d_ws;
    unsigned int* am = (unsigned int*)wsb;
    char* WQ  = wsb + 256;
    char* XNQ = WQ + 2359296;                 // int8 slot (ln out / xaq / hq-side)
    char* BIG = XNQ + nA;
    unsigned short* QKV = (unsigned short*)BIG;
    unsigned short* XA  = (unsigned short*)(BIG + 2*nQ);
    unsigned short* Hbf = (unsigned short*)BIG;
    char* HQ = BIG;                           // in-place int8 h (rows >= SPLIT)

    const int SPLIT = 4608;                   // h rows [0,SPLIT) live in XNQ slot
    const size_t rowsB = 9216 - 4608, rowsC = 18432 - 9216, rowsD = 18464 - 18432;

    dim3 blk(256);
    int mt128 = (M + 127) / 128;

    init_slots<<<dim3(1), dim3(16), 0, stream>>>(am);

    // ---- attention branch ----
    ln_absmax<<<dim3(2048), blk, 0, stream>>>(x, ln1_g, ln1_b, M, am + 0);
    ln_quant <<<dim3(2048), blk, 0, stream>>>(x, ln1_g, ln1_b, M, XNQ, am + 0);

    absmax_f32<<<dim3(1024), blk, 0, stream>>>(qkv_w, (size_t)3*C*C, am + 6);
    quant_w  <<<dim3(1024), blk, 0, stream>>>(qkv_w, WQ, (size_t)3*C*C, am + 6);
    gemm_i8<<<dim3(3*C/128, mt128), blk, 0, stream>>>(
        XNQ, XNQ, 0, WQ, qkv_b, nullptr, QKV, M, 3*C, C,
        am + 0, 2e-8f, am + 6, 0, 1, nullptr);

    attn_mfma<<<dim3(10, 384), blk, 0, stream>>>(QKV, XA, am + 2);

    // xa -> int8 (XNQ slot is dead here; proj consumes it before ln2 rewrites it)
    quant_bf2i8<<<dim3(2048), blk, 0, stream>>>(XA, XNQ, nA/8, am + 2);

    absmax_f32<<<dim3(1024), blk, 0, stream>>>(proj_w, (size_t)C*C, am + 7);
    quant_w  <<<dim3(1024), blk, 0, stream>>>(proj_w, WQ, (size_t)C*C, am + 7);
    gemm_i8<<<dim3(C/128, mt128), blk, 0, stream>>>(
        XNQ, XNQ, 0, WQ, proj_b, x, out, M, C, C,
        am + 2, 1e-8f, am + 7, 0, 0, nullptr);          // out = x + proj

    // ---- mlp branch ----
    ln_absmax<<<dim3(2048), blk, 0, stream>>>(out, ln2_g, ln2_b, M, am + 4);
    ln_quant <<<dim3(2048), blk, 0, stream>>>(out, ln2_g, ln2_b, M, XNQ, am + 4);

    absmax_f32<<<dim3(1024), blk, 0, stream>>>(fc1_w, (size_t)H3*C, am + 8);
    quant_w  <<<dim3(1024), blk, 0, stream>>>(fc1_w, WQ, (size_t)H3*C, am + 8);
    gemm_i8<<<dim3(H3/128, mt128), blk, 0, stream>>>(
        XNQ, XNQ, 0, WQ, fc1_b, nullptr, Hbf, M, H3, C,
        am + 4, 2e-8f, am + 8, 1, 1, am + 3);           // gelu, bf16 h, absmax(h)

    // h -> int8: side chunk to XNQ slot, then in-place compaction (ordered,
    // write/read byte ranges disjoint per launch)
    quant_bf2i8<<<dim3(2048), blk, 0, stream>>>(
        Hbf, XNQ, (size_t)SPLIT*H3/8, am + 3);
    quant_bf2i8<<<dim3(2048), blk, 0, stream>>>(
        Hbf + (size_t)4608*H3, HQ + (size_t)4608*H3, rowsB*H3/8, am + 3);
    quant_bf2i8<<<dim3(2048), blk, 0, stream>>>(
        Hbf + (size_t)9216*H3, HQ + (size_t)9216*H3, rowsC*H3/8, am + 3);
    quant_bf2i8<<<dim3(48),  blk, 0, stream>>>(
        Hbf + (size_t)18432*H3, HQ + (size_t)18432*H3, rowsD*H3/8, am + 3);

    absmax_f32<<<dim3(1024), blk, 0, stream>>>(fc2_w, (size_t)C*H3, am + 9);
    quant_w  <<<dim3(1024), blk, 0, stream>>>(fc2_w, WQ, (size_t)C*H3, am + 9);
    gemm_i8<<<dim3(C/128, mt128), blk, 0, stream>>>(
        XNQ, HQ, SPLIT, WQ, fc2_b, out, out, M, C, H3,
        am + 3, 1e-8f, am + 9, 0, 0, nullptr);          // out += fc2
}